// Round 3
// baseline (591.672 us; speedup 1.0000x reference)
//
#include <hip/hip_runtime.h>
#include <hip/hip_bf16.h>

using bf16 = __hip_bfloat16;
using frag8 = __attribute__((ext_vector_type(8))) short;  // 8 bf16 (4 VGPRs)
using f32x4 = __attribute__((ext_vector_type(4))) float;  // MFMA C/D

__device__ __forceinline__ short f2bf_bits(float f) {
  bf16 h = __float2bfloat16(f);
  short s; __builtin_memcpy(&s, &h, 2); return s;
}
__device__ __forceinline__ float bfbits2f(unsigned short u) {
  unsigned uu = (unsigned)u << 16; float f; __builtin_memcpy(&f, &uu, 4); return f;
}
__device__ __forceinline__ float wred_sum(float v) {
#pragma unroll
  for (int o = 32; o; o >>= 1) v += __shfl_xor(v, o);
  return v;
}
__device__ __forceinline__ float rfl_f(float v) {
  int i; __builtin_memcpy(&i, &v, 4);
  i = __builtin_amdgcn_readfirstlane(i);
  float f; __builtin_memcpy(&f, &i, 4); return f;
}

// ================= prep: flag-detect + param canonicalize + wtilde fold +
// cnt zeroing, all in ONE dispatch (each block self-detects the dtype flag
// from the first 16KB of x_A).
struct ConvJob { const void* src; void* dst; int n; int mode; int ksh; };
struct ConvJobs { ConvJob j[28]; };
struct WtJob { const void* wraw; const void* adraw; bf16* out; int H; };
struct WtJobs4 { WtJob j[4]; };

__global__ __launch_bounds__(256) void prep_k(
    const unsigned* __restrict__ xdet, int* __restrict__ flag,
    ConvJobs cjobs, int ncv, WtJobs4 wjobs,
    int* __restrict__ cntA, int nA, int* __restrict__ cntB, int nB)
{
  const int b = blockIdx.x, tid = threadIdx.x;
  if (b >= ncv + 4) {                         // cnt zero region (no flag needed)
    int i = (b - (ncv + 4)) * 256 + tid;
    if (i < nA) cntA[i] = 0;
    else if (i < nA + nB) cntB[i - nA] = 0;
    return;
  }
  __shared__ int sh[256];
  int c = 0;
  for (int i = tid; i < 4096; i += 256) {
    unsigned bb = (xdet[i] >> 8) & 0x7F;
    c += (bb >= 0x3B && bb <= 0x41) ? 1 : 0;
  }
  sh[tid] = c; __syncthreads();
  for (int off = 128; off; off >>= 1) { if (tid < off) sh[tid] += sh[tid + off]; __syncthreads(); }
  const int f = (sh[0] < 2048) ? 1 : 0;
  if (b == 0 && tid == 0) flag[0] = f;

  if (b < ncv) {                              // canonicalize job
    ConvJob J = cjobs.j[b];
    const int Kt = 1 << J.ksh;
    for (int i = tid; i < J.n; i += 256) {
      int si = i;
      if (J.mode == 1) { int n = i >> J.ksh, k = i & (Kt - 1); si = k * 128 + n; }
      float v = f ? ((const float*)J.src)[si] : bfbits2f(((const unsigned short*)J.src)[si]);
      if (J.mode == 1) ((bf16*)J.dst)[i] = __float2bfloat16(v);
      else             ((float*)J.dst)[i] = v;
    }
  } else {                                    // wtilde fold from RAW W and ad
    WtJob J = wjobs.j[b - ncv];               // Wt2[h][k] = sum_d W[k][h*D+d]*ad[h*D+d]
    const int H = J.H, D = 128 / H;
    for (int idx = tid; idx < 16 * 128; idx += 256) {
      int h = idx >> 7, k = idx & 127;
      float s = 0.f;
      if (h < H) {
        for (int d = 0; d < D; d++) {
          int n = h * D + d;
          float wv = f ? ((const float*)J.wraw)[k * 128 + n]
                       : bfbits2f(((const unsigned short*)J.wraw)[k * 128 + n]);
          float av = f ? ((const float*)J.adraw)[n]
                       : bfbits2f(((const unsigned short*)J.adraw)[n]);
          s += wv * av;
        }
      }
      J.out[idx] = __float2bfloat16(s);
    }
  }
}

// ================= GEMM body (shared by several merged kernels) =============
struct GemmJob {
  const void* Av; const bf16* WT; const float* bias; const float* avec;
  bf16* outFull; float* outScore; const int* flagp;
  const bf16* WT2; float* outScore2;
  int M, K, H, H2;
};
__device__ __forceinline__ void gemm_body(const GemmJob& J, int blk) {
  __shared__ __align__(16) bf16 Wt[128 * 136];
  __shared__ __align__(16) bf16 Wt2s[16 * 136];
  const int tid = threadIdx.x;
  const int K = J.K;
  const int isf32 = J.flagp ? J.flagp[0] : 0;
  const int stride = K + 8;
  const int ksh2 = (K == 128) ? 4 : 3;
  const int kunits = K >> 3;
  for (int u = tid; u < 128 * kunits; u += 256) {
    int n = u >> ksh2, kb = u & (kunits - 1);
    frag8 v = *(const frag8*)(J.WT + n * K + kb * 8);
    *(frag8*)(Wt + n * stride + kb * 8) = v;
  }
  if (J.WT2) {
    int n = tid >> 4, kb = tid & 15;
    *(frag8*)(Wt2s + n * 136 + kb * 8) = *(const frag8*)(J.WT2 + n * 128 + kb * 8);
  }
  __syncthreads();

  const int lane = tid & 63, wave = tid >> 6;
  const int quad = lane >> 4, c = lane & 15;
  const int mbase = blk * 64 + wave * 16;
  const int arow = mbase + c;
  const bool rowOK = arow < J.M;

  f32x4 acc[8];
#pragma unroll
  for (int t = 0; t < 8; t++) acc[t] = (f32x4){0.f, 0.f, 0.f, 0.f};
  f32x4 acc2 = (f32x4){0.f, 0.f, 0.f, 0.f};

  for (int ks = 0; ks < K; ks += 32) {
    frag8 af;
    const int k0 = ks + quad * 8;
    if (rowOK) {
      if (isf32) {
        const float4* ap = (const float4*)((const float*)J.Av + (size_t)arow * K + k0);
        float4 v0 = ap[0], v1 = ap[1];
        af[0] = f2bf_bits(v0.x); af[1] = f2bf_bits(v0.y);
        af[2] = f2bf_bits(v0.z); af[3] = f2bf_bits(v0.w);
        af[4] = f2bf_bits(v1.x); af[5] = f2bf_bits(v1.y);
        af[6] = f2bf_bits(v1.z); af[7] = f2bf_bits(v1.w);
      } else {
        af = *(const frag8*)((const bf16*)J.Av + (size_t)arow * K + k0);
      }
    } else {
#pragma unroll
      for (int j = 0; j < 8; j++) af[j] = 0;
    }
#pragma unroll
    for (int t = 0; t < 8; t++) {
      frag8 bfv = *(const frag8*)(Wt + (t * 16 + c) * stride + k0);
      acc[t] = __builtin_amdgcn_mfma_f32_16x16x32_bf16(af, bfv, acc[t], 0, 0, 0);
    }
    if (J.WT2) {
      frag8 b2 = *(const frag8*)(Wt2s + c * 136 + k0);
      acc2 = __builtin_amdgcn_mfma_f32_16x16x32_bf16(af, b2, acc2, 0, 0, 0);
    }
  }

  if (J.outFull) {
#pragma unroll
    for (int t = 0; t < 8; t++) {
#pragma unroll
      for (int r = 0; r < 4; r++) {
        int orow = mbase + quad * 4 + r;
        if (orow < J.M) {
          float v = acc[t][r];
          if (J.bias) v += J.bias[t * 16 + c];
          J.outFull[(size_t)orow * 128 + t * 16 + c] = __float2bfloat16(v);
        }
      }
    }
  }
  if (J.outScore) {
    const int H = J.H;
    const int TPH = 8 / H;
    for (int hh = 0; hh < H; hh++) {
#pragma unroll
      for (int r = 0; r < 4; r++) {
        float p = 0.f;
        for (int tt = 0; tt < TPH; tt++) {
          int t = hh * TPH + tt;
          p += acc[t][r] * J.avec[t * 16 + c];
        }
#pragma unroll
        for (int off = 1; off < 16; off <<= 1) p += __shfl_xor(p, off);
        int orow = mbase + quad * 4 + r;
        if (c == 0 && orow < J.M) J.outScore[(size_t)orow * H + hh] = p;
      }
    }
  }
  if (J.outScore2) {
#pragma unroll
    for (int r = 0; r < 4; r++) {
      int orow = mbase + quad * 4 + r;
      if (c < J.H2 && orow < J.M) J.outScore2[(size_t)orow * J.H2 + c] = acc2[r];
    }
  }
}

// ================= hist ∥ proj-GEMM (one dispatch) ==========================
__global__ __launch_bounds__(256) void histgemm_k(
    GemmJob ja, GemmJob jb, int gsplit,
    const int* __restrict__ dAB, const int* __restrict__ dBA, int E, int geh,
    int* __restrict__ cntB, int* __restrict__ cntA)
{
  const int b = blockIdx.x;
  if (b < 2 * geh) {
    if (b < geh) { int i = b * 256 + threadIdx.x; if (i < E) atomicAdd(&cntB[dAB[i]], 1); }
    else { int i = (b - geh) * 256 + threadIdx.x; if (i < E) atomicAdd(&cntA[dBA[i]], 1); }
    return;
  }
  const int gb = b - 2 * geh;
  if (gb < gsplit) gemm_body(ja, gb);
  else             gemm_body(jb, gb - gsplit);
}

// ================= fused scan (blocksum+scan+writerp in 1 block/dir) ========
__device__ __forceinline__ void scanfull_body(const int* __restrict__ cnt, int N,
                                              int* __restrict__ rp, int* __restrict__ cur) {
  __shared__ int sh[256];
  const int tid = threadIdx.x;
  const int seg = (N + 255) / 256;
  const int b0 = tid * seg < N ? tid * seg : N;
  const int b1 = (tid + 1) * seg < N ? (tid + 1) * seg : N;
  int loc = 0;
  for (int i = b0; i < b1; i++) loc += cnt[i];
  sh[tid] = loc; __syncthreads();
  for (int off = 1; off < 256; off <<= 1) {
    int x = sh[tid];
    int o = (tid >= off) ? sh[tid - off] : 0;
    __syncthreads();
    sh[tid] = x + o;
    __syncthreads();
  }
  int run = (tid == 0) ? 0 : sh[tid - 1];
  for (int i = b0; i < b1; i++) { rp[i] = run; cur[i] = run; run += cnt[i]; }
  if (tid == 255) rp[N] = run;
}
__global__ __launch_bounds__(256) void scangemm_k(
    GemmJob ja, GemmJob jb, int gsplit,
    const int* __restrict__ cntB, int NB, int* __restrict__ rpAB, int* __restrict__ curB,
    const int* __restrict__ cntA, int NA, int* __restrict__ rpBA, int* __restrict__ curA)
{
  const int b = blockIdx.x;
  if (b < 2) {
    if (b == 0) scanfull_body(cntB, NB, rpAB, curB);
    else        scanfull_body(cntA, NA, rpBA, curA);
    return;
  }
  const int gb = b - 2;
  if (gb < gsplit) gemm_body(ja, gb);
  else             gemm_body(jb, gb - gsplit);
}

// plain dual-GEMM dispatch (layer 1)
__global__ __launch_bounds__(256) void gemm2_k(GemmJob ja, GemmJob jb, int split) {
  if (blockIdx.x < split) gemm_body(ja, blockIdx.x);
  else                    gemm_body(jb, blockIdx.x - split);
}

// ================= XCD-partitioned scatter ==================================
// 8 block-groups (blockIdx%8 ~ XCD); each group owns a disjoint dst range so
// cur[] atomics and sl[] lines stay XCD-local (kills cross-XCD write thrash).
// Correctness does NOT depend on the blockIdx->XCD mapping, only locality.
__global__ __launch_bounds__(256) void scatter8_k(
    const int* __restrict__ sAB, const int* __restrict__ dAB,
    const int* __restrict__ sBA, const int* __restrict__ dBA, int E,
    int* __restrict__ curB, int* __restrict__ slAB,
    int* __restrict__ curA, int* __restrict__ slBA, int NB, int NA)
{
  const int g = blockIdx.x & 7;
  const int sidx = blockIdx.x >> 3;
  const int loB = (int)((long long)NB * g >> 3), hiB = (int)((long long)NB * (g + 1) >> 3);
  const int loA = (int)((long long)NA * g >> 3), hiA = (int)((long long)NA * (g + 1) >> 3);
  const int b0 = sidx * 2048;
#pragma unroll
  for (int j = 0; j < 8; j++) {
    int i = b0 + j * 256 + threadIdx.x;
    if (i < 2 * E) {
      bool ab = i < E;
      int k = ab ? i : i - E;
      int d = ab ? dAB[k] : dBA[k];
      int lo = ab ? loB : loA, hi = ab ? hiB : hiA;
      if (d >= lo && d < hi) {
        int sv = ab ? sAB[k] : sBA[k];
        int pos = atomicAdd((ab ? curB : curA) + d, 1);
        (ab ? slAB : slBA)[pos] = sv;
      }
    }
  }
}

// ================= GAT aggregate ============================================
struct AggJob {
  const int* rp; const int* srcl; const float* as_; const float* ad_;
  const bf16* hs; const float* bias; const float* gamma; const float* beta;
  const bf16* resid; bf16* outBf; void* outFinal; const int* flagp;
  int nodeBase, N;
};

template<bool FINAL>
__device__ __forceinline__ void agg_epilogue(const AggJob& J, int n, int lane,
                                             float inv, float acc0, float acc1) {
  float2 bi = *(const float2*)(J.bias + 2 * lane);
  float y0 = acc0 * inv + bi.x;
  float y1 = acc1 * inv + bi.y;
  float tsum = wred_sum(y0 + y1);
  float tsq  = wred_sum(y0 * y0 + y1 * y1);
  float mu = tsum * 0.0078125f;
  float var = tsq * 0.0078125f - mu * mu;
  float rs = rsqrtf(var + 1e-5f);
  float2 ga = *(const float2*)(J.gamma + 2 * lane);
  float2 be = *(const float2*)(J.beta + 2 * lane);
  float z0 = (y0 - mu) * rs * ga.x + be.x;
  float z1 = (y1 - mu) * rs * ga.y + be.y;
  unsigned ru = *(const unsigned*)(J.resid + (size_t)n * 128 + 2 * lane);
  z0 = fmaxf(z0, 0.f) + bfbits2f((unsigned short)(ru & 0xFFFF));
  z1 = fmaxf(z1, 0.f) + bfbits2f((unsigned short)(ru >> 16));
  if constexpr (FINAL) {
    size_t oi = (size_t)(J.nodeBase + n) * 128 + 2 * lane;
    if (J.flagp[0]) {
      *(float2*)((float*)J.outFinal + oi) = make_float2(z0, z1);
    } else {
      unsigned short l0 = (unsigned short)f2bf_bits(z0);
      unsigned short l1 = (unsigned short)f2bf_bits(z1);
      *(unsigned*)((bf16*)J.outFinal + oi) = (unsigned)l0 | ((unsigned)l1 << 16);
    }
  } else {
    unsigned short l0 = (unsigned short)f2bf_bits(z0);
    unsigned short l1 = (unsigned short)f2bf_bits(z1);
    *(unsigned*)(J.outBf + (size_t)n * 128 + 2 * lane) = (unsigned)l0 | ((unsigned)l1 << 16);
  }
}

// H=4: phase-1 LDS p-staging (parallel exp); inner loop with readfirstlane'd
// wave/src so addressing is SALU and the gather uses an SGPR base.
template<bool FINAL>
__global__ __launch_bounds__(256) void agg4_k(AggJob JA, AggJob JB, int split) {
  const bool first = blockIdx.x < split;
  const AggJob J = first ? JA : JB;
  const int blk = first ? blockIdx.x : blockIdx.x - split;

  __shared__ float s_p[4][64 * 4];
  const int lane = threadIdx.x & 63;
  const int wave = __builtin_amdgcn_readfirstlane(threadIdx.x >> 6);
  const int n = blk * 4 + wave;                // uniform
  if (n >= J.N) return;

  const int beg = __builtin_amdgcn_readfirstlane(J.rp[n]);
  const int end = __builtin_amdgcn_readfirstlane(J.rp[n + 1]);
  const int myh = lane >> 4;
  const float4 adv = *(const float4*)(J.ad_ + (size_t)n * 4);
  float sl0 = 0.f, sl1 = 0.f, sl2 = 0.f, sl3 = 0.f;
  float acc0 = 0.f, acc1 = 0.f;
  const int* srcp = J.srcl;
  const bf16* hsp = J.hs;

  for (int base = beg; base < end; base += 64) {
    const int cn = (end - base < 64) ? end - base : 64;
    if (lane < cn) {
      int s = srcp[base + lane];
      float4 a = *(const float4*)(J.as_ + (size_t)s * 4);
      float4 o; float v;
      v = a.x + adv.x; v = v > 0.f ? v : 0.2f * v; o.x = __expf(v);
      v = a.y + adv.y; v = v > 0.f ? v : 0.2f * v; o.y = __expf(v);
      v = a.z + adv.z; v = v > 0.f ? v : 0.2f * v; o.z = __expf(v);
      v = a.w + adv.w; v = v > 0.f ? v : 0.2f * v; o.w = __expf(v);
      *(float4*)&s_p[wave][lane * 4] = o;
      sl0 += o.x; sl1 += o.y; sl2 += o.z; sl3 += o.w;
    }
    __builtin_amdgcn_wave_barrier();
#pragma unroll 4
    for (int e = 0; e < cn; e++) {
      const int src = __builtin_amdgcn_readfirstlane(srcp[base + e]);
      const float p = s_p[wave][e * 4 + myh];
      const unsigned u = *(const unsigned*)(hsp + (size_t)src * 128 + 2 * lane);
      acc0 += p * bfbits2f((unsigned short)(u & 0xFFFF));
      acc1 += p * bfbits2f((unsigned short)(u >> 16));
    }
    __builtin_amdgcn_wave_barrier();
  }

  float t0 = wred_sum(sl0), t1 = wred_sum(sl1), t2 = wred_sum(sl2), t3 = wred_sum(sl3);
  float s = (myh == 0) ? t0 : (myh == 1) ? t1 : (myh == 2) ? t2 : t3;
  const float inv = 1.f / (s + 1e-16f);
  agg_epilogue<FINAL>(J, n, lane, inv, acc0, acc1);
}

// H=1: fully scalar edge loop — src/as via uniform (scalar) loads, p computed
// inline (no LDS, no barriers, softmax denom is uniform so no reduction).
template<bool FINAL>
__global__ __launch_bounds__(256) void agg1_k(AggJob JA, AggJob JB, int split) {
  const bool first = blockIdx.x < split;
  const AggJob J = first ? JA : JB;
  const int blk = first ? blockIdx.x : blockIdx.x - split;

  const int lane = threadIdx.x & 63;
  const int wave = __builtin_amdgcn_readfirstlane(threadIdx.x >> 6);
  const int n = blk * 4 + wave;                // uniform
  if (n >= J.N) return;

  const int beg = __builtin_amdgcn_readfirstlane(J.rp[n]);
  const int end = __builtin_amdgcn_readfirstlane(J.rp[n + 1]);
  const float adn = rfl_f(J.ad_[n]);
  float sum = 0.f, acc0 = 0.f, acc1 = 0.f;
  const int* srcp = J.srcl;
  const float* asp = J.as_;
  const bf16* hsp = J.hs;

#pragma unroll 4
  for (int e = beg; e < end; e++) {
    const int src = __builtin_amdgcn_readfirstlane(srcp[e]);
    float v = rfl_f(asp[src]) + adn;
    v = v > 0.f ? v : 0.2f * v;
    const float p = __expf(v);
    sum += p;
    const unsigned u = *(const unsigned*)(hsp + (size_t)src * 128 + 2 * lane);
    acc0 += p * bfbits2f((unsigned short)(u & 0xFFFF));
    acc1 += p * bfbits2f((unsigned short)(u >> 16));
  }
  const float inv = 1.f / (sum + 1e-16f);
  agg_epilogue<FINAL>(J, n, lane, inv, acc0, acc1);
}

extern "C" void kernel_launch(void* const* d_in, const int* in_sizes, int n_in,
                              void* d_out, int out_size, void* d_ws, size_t ws_size,
                              hipStream_t stream)
{
  const int NA = in_sizes[0] / 128;
  const int NB = in_sizes[1] / 64;
  const int E  = in_sizes[30] / 2;
  const int* eiAB = (const int*)d_in[30];
  const int* eiBA = (const int*)d_in[31];
  const int* srcAB = eiAB;  const int* dstAB = eiAB + E;
  const int* srcBA = eiBA;  const int* dstBA = eiBA + E;

  char* w = (char*)d_ws;
  size_t used = 0;
  auto alloc = [&](size_t bytes) {
    char* p = w + used;
    used += (bytes + 255) & ~size_t(255);
    return (void*)p;
  };
  int*  flag  = (int*)alloc(256);
  bf16* WcA   = (bf16*)alloc(16384 * 2);
  bf16* WcB   = (bf16*)alloc(8192 * 2);
  bf16* Wc0ab = (bf16*)alloc(16384 * 2);
  bf16* Wc0ba = (bf16*)alloc(16384 * 2);
  bf16* Wc1ab = (bf16*)alloc(16384 * 2);
  bf16* Wc1ba = (bf16*)alloc(16384 * 2);
  bf16* Wt0ab = (bf16*)alloc(16 * 128 * 2);    // folded W*ad tiles
  bf16* Wt0ba = (bf16*)alloc(16 * 128 * 2);
  bf16* Wt1ab = (bf16*)alloc(16 * 128 * 2);
  bf16* Wt1ba = (bf16*)alloc(16 * 128 * 2);
  float* vec  = (float*)alloc(22 * 128 * 4);
  bf16* hA    = (bf16*)alloc((size_t)NA * 128 * 2);
  bf16* hB    = (bf16*)alloc((size_t)NB * 128 * 2);
  bf16* hsAB  = (bf16*)alloc((size_t)NA * 128 * 2);
  bf16* hsBA  = (bf16*)alloc((size_t)NB * 128 * 2);
  float* asAB = (float*)alloc((size_t)NA * 4 * 4);
  float* adAB = (float*)alloc((size_t)NB * 4 * 4);
  float* asBA = (float*)alloc((size_t)NB * 4 * 4);
  float* adBA = (float*)alloc((size_t)NA * 4 * 4);
  int* rpAB = (int*)alloc((size_t)(NB + 1) * 4);
  int* slAB = (int*)alloc((size_t)E * 4);
  int* rpBA = (int*)alloc((size_t)(NA + 1) * 4);
  int* slBA = (int*)alloc((size_t)E * 4);
  int* cntA = (int*)alloc((size_t)NA * 4);
  int* curA = (int*)alloc((size_t)NA * 4);
  int* cntB = (int*)alloc((size_t)NB * 4);
  int* curB = (int*)alloc((size_t)NB * 4);
  if (used > ws_size) return;  // diagnostic: absmax would equal max|ref| (~6.84)

  auto V = [&](int i) { return vec + 128 * i; };
  // vec slots: 0 pbA, 1 pbB, 2 as0ab, 3 ad0ab, 4 b0ab, 5 as0ba, 6 ad0ba,
  // 7 b0ba, 8 as1ab, 9 ad1ab, 10 b1ab, 11 as1ba, 12 ad1ba, 13 b1ba,
  // 14 g0A, 15 bn0A, 16 g0B, 17 bn0B, 18 g1A, 19 bn1A, 20 g1B, 21 bn1B

  ConvJobs jobs{};
  int nj = 0;
  auto addT = [&](const void* s, void* d, int K) {
    int ksh = (K == 128) ? 7 : 6;
    jobs.j[nj++] = ConvJob{s, d, 128 * K, 1, ksh};
  };
  auto addV = [&](const void* s, void* d) { jobs.j[nj++] = ConvJob{s, d, 128, 0, 7}; };
  addT(d_in[2], WcA, 128);
  addT(d_in[4], WcB, 64);
  addT(d_in[6], Wc0ab, 128);
  addT(d_in[10], Wc0ba, 128);
  addT(d_in[14], Wc1ab, 128);
  addT(d_in[18], Wc1ba, 128);
  const int vsrc[22] = {3, 5, 7, 8, 9, 11, 12, 13, 15, 16, 17, 19, 20, 21, 22, 23, 24, 25, 26, 27, 28, 29};
  for (int i = 0; i < 22; i++) addV(d_in[vsrc[i]], V(i));

  WtJobs4 wj{};
  wj.j[0] = WtJob{d_in[6],  d_in[8],  Wt0ab, 4};
  wj.j[1] = WtJob{d_in[10], d_in[12], Wt0ba, 4};
  wj.j[2] = WtJob{d_in[14], d_in[16], Wt1ab, 1};
  wj.j[3] = WtJob{d_in[18], d_in[20], Wt1ba, 1};

  const int nz = (NA + NB + 255) / 256;
  // D1: prep (flag, canonicalize, wtilde, cnt zero)
  prep_k<<<nj + 4 + nz, 256, 0, stream>>>((const unsigned*)d_in[0], flag, jobs, nj, wj,
                                          cntA, NA, cntB, NB);

  const int geh = (E + 255) / 256;
  const int gA = (NA + 63) / 64, gB = (NB + 63) / 64;
  const int aA = (NA + 3) / 4, aB = (NB + 3) / 4;

  // D2: hist (both dirs) ∥ input-projection GEMMs
  {
    GemmJob ja{d_in[0], WcA, V(0), nullptr, hA, nullptr, flag, nullptr, nullptr, NA, 128, 1, 0};
    GemmJob jb{d_in[1], WcB, V(1), nullptr, hB, nullptr, flag, nullptr, nullptr, NB, 64, 1, 0};
    histgemm_k<<<2 * geh + gA + gB, 256, 0, stream>>>(ja, jb, gA, dstAB, dstBA, E, geh,
                                                      cntB, cntA);
  }
  // D3: fused scan (2 blocks) ∥ layer-0 GEMMs (emit opposite-dir dst-scores)
  {
    GemmJob ja{hA, Wc0ab, nullptr, V(2), hsAB, asAB, nullptr, Wt0ba, adBA, NA, 128, 4, 4};
    GemmJob jb{hB, Wc0ba, nullptr, V(5), hsBA, asBA, nullptr, Wt0ab, adAB, NB, 128, 4, 4};
    scangemm_k<<<2 + gA + gB, 256, 0, stream>>>(ja, jb, gA,
                                                cntB, NB, rpAB, curB,
                                                cntA, NA, rpBA, curA);
  }
  // D4: XCD-partitioned scatter (both dirs)
  {
    const int nsl = (2 * E + 2047) / 2048;
    scatter8_k<<<8 * nsl, 256, 0, stream>>>(srcAB, dstAB, srcBA, dstBA, E,
                                            curB, slAB, curA, slBA, NB, NA);
  }
  // D5: layer-0 aggregate (H=4, both dirs)
  {
    AggJob ja{rpAB, slAB, asAB, adAB, hsAB, V(4), V(16), V(17), hB, hB, nullptr, nullptr, 0, NB};
    AggJob jb{rpBA, slBA, asBA, adBA, hsBA, V(7), V(14), V(15), hA, hA, nullptr, nullptr, 0, NA};
    agg4_k<false><<<aB + aA, 256, 0, stream>>>(ja, jb, aB);
  }
  // D6: layer-1 GEMMs
  {
    GemmJob ja{hA, Wc1ab, nullptr, V(8),  hsAB, asAB, nullptr, Wt1ba, adBA, NA, 128, 1, 1};
    GemmJob jb{hB, Wc1ba, nullptr, V(11), hsBA, asBA, nullptr, Wt1ab, adAB, NB, 128, 1, 1};
    gemm2_k<<<gA + gB, 256, 0, stream>>>(ja, jb, gA);
  }
  // D7: layer-1 aggregate (H=1, both dirs, final output)
  {
    AggJob ja{rpAB, slAB, asAB, adAB, hsAB, V(10), V(20), V(21), hB, nullptr, d_out, flag, NA, NB};
    AggJob jb{rpBA, slBA, asBA, adBA, hsBA, V(13), V(18), V(19), hA, nullptr, d_out, flag, 0, NA};
    agg1_k<true><<<aB + aA, 256, 0, stream>>>(ja, jb, aB);
  }
}

// Round 4
// 505.574 us; speedup vs baseline: 1.1703x; 1.1703x over previous
//
#include <hip/hip_runtime.h>
#include <hip/hip_bf16.h>

using bf16 = __hip_bfloat16;
using frag8 = __attribute__((ext_vector_type(8))) short;  // 8 bf16 (4 VGPRs)
using f32x4 = __attribute__((ext_vector_type(4))) float;  // MFMA C/D

__device__ __forceinline__ short f2bf_bits(float f) {
  bf16 h = __float2bfloat16(f);
  short s; __builtin_memcpy(&s, &h, 2); return s;
}
__device__ __forceinline__ float bfbits2f(unsigned short u) {
  unsigned uu = (unsigned)u << 16; float f; __builtin_memcpy(&f, &uu, 4); return f;
}
__device__ __forceinline__ float wred_sum(float v) {
#pragma unroll
  for (int o = 32; o; o >>= 1) v += __shfl_xor(v, o);
  return v;
}
__device__ __forceinline__ float rfl_f(float v) {
  int i; __builtin_memcpy(&i, &v, 4);
  i = __builtin_amdgcn_readfirstlane(i);
  float f; __builtin_memcpy(&f, &i, 4); return f;
}

// ================= prep: flag-detect + param canonicalize + wtilde fold +
// cnt zeroing, all in ONE dispatch (each block self-detects the dtype flag
// from the first 16KB of x_A).
struct ConvJob { const void* src; void* dst; int n; int mode; int ksh; };
struct ConvJobs { ConvJob j[28]; };
struct WtJob { const void* wraw; const void* adraw; bf16* out; int H; };
struct WtJobs4 { WtJob j[4]; };

__global__ __launch_bounds__(256) void prep_k(
    const unsigned* __restrict__ xdet, int* __restrict__ flag,
    ConvJobs cjobs, int ncv, WtJobs4 wjobs,
    int* __restrict__ cntA, int nA, int* __restrict__ cntB, int nB)
{
  const int b = blockIdx.x, tid = threadIdx.x;
  if (b >= ncv + 4) {                         // cnt zero region (no flag needed)
    int i = (b - (ncv + 4)) * 256 + tid;
    if (i < nA) cntA[i] = 0;
    else if (i < nA + nB) cntB[i - nA] = 0;
    return;
  }
  __shared__ int sh[256];
  int c = 0;
  for (int i = tid; i < 4096; i += 256) {
    unsigned bb = (xdet[i] >> 8) & 0x7F;
    c += (bb >= 0x3B && bb <= 0x41) ? 1 : 0;
  }
  sh[tid] = c; __syncthreads();
  for (int off = 128; off; off >>= 1) { if (tid < off) sh[tid] += sh[tid + off]; __syncthreads(); }
  const int f = (sh[0] < 2048) ? 1 : 0;
  if (b == 0 && tid == 0) flag[0] = f;

  if (b < ncv) {                              // canonicalize job
    ConvJob J = cjobs.j[b];
    const int Kt = 1 << J.ksh;
    for (int i = tid; i < J.n; i += 256) {
      int si = i;
      if (J.mode == 1) { int n = i >> J.ksh, k = i & (Kt - 1); si = k * 128 + n; }
      float v = f ? ((const float*)J.src)[si] : bfbits2f(((const unsigned short*)J.src)[si]);
      if (J.mode == 1) ((bf16*)J.dst)[i] = __float2bfloat16(v);
      else             ((float*)J.dst)[i] = v;
    }
  } else {                                    // wtilde fold from RAW W and ad
    WtJob J = wjobs.j[b - ncv];               // Wt2[h][k] = sum_d W[k][h*D+d]*ad[h*D+d]
    const int H = J.H, D = 128 / H;
    for (int idx = tid; idx < 16 * 128; idx += 256) {
      int h = idx >> 7, k = idx & 127;
      float s = 0.f;
      if (h < H) {
        for (int d = 0; d < D; d++) {
          int n = h * D + d;
          float wv = f ? ((const float*)J.wraw)[k * 128 + n]
                       : bfbits2f(((const unsigned short*)J.wraw)[k * 128 + n]);
          float av = f ? ((const float*)J.adraw)[n]
                       : bfbits2f(((const unsigned short*)J.adraw)[n]);
          s += wv * av;
        }
      }
      J.out[idx] = __float2bfloat16(s);
    }
  }
}

// ================= GEMM body (shared by merged kernels) =====================
struct GemmJob {
  const void* Av; const bf16* WT; const float* bias; const float* avec;
  bf16* outFull; float* outScore; const int* flagp;
  const bf16* WT2; float* outScore2;
  int M, K, H, H2;
};
__device__ __forceinline__ void gemm_body(const GemmJob& J, int blk) {
  __shared__ __align__(16) bf16 Wt[128 * 136];
  __shared__ __align__(16) bf16 Wt2s[16 * 136];
  const int tid = threadIdx.x;
  const int K = J.K;
  const int isf32 = J.flagp ? J.flagp[0] : 0;
  const int stride = K + 8;
  const int ksh2 = (K == 128) ? 4 : 3;
  const int kunits = K >> 3;
  for (int u = tid; u < 128 * kunits; u += 256) {
    int n = u >> ksh2, kb = u & (kunits - 1);
    frag8 v = *(const frag8*)(J.WT + n * K + kb * 8);
    *(frag8*)(Wt + n * stride + kb * 8) = v;
  }
  if (J.WT2) {
    int n = tid >> 4, kb = tid & 15;
    *(frag8*)(Wt2s + n * 136 + kb * 8) = *(const frag8*)(J.WT2 + n * 128 + kb * 8);
  }
  __syncthreads();

  const int lane = tid & 63, wave = tid >> 6;
  const int quad = lane >> 4, c = lane & 15;
  const int mbase = blk * 64 + wave * 16;
  const int arow = mbase + c;
  const bool rowOK = arow < J.M;

  f32x4 acc[8];
#pragma unroll
  for (int t = 0; t < 8; t++) acc[t] = (f32x4){0.f, 0.f, 0.f, 0.f};
  f32x4 acc2 = (f32x4){0.f, 0.f, 0.f, 0.f};

  for (int ks = 0; ks < K; ks += 32) {
    frag8 af;
    const int k0 = ks + quad * 8;
    if (rowOK) {
      if (isf32) {
        const float4* ap = (const float4*)((const float*)J.Av + (size_t)arow * K + k0);
        float4 v0 = ap[0], v1 = ap[1];
        af[0] = f2bf_bits(v0.x); af[1] = f2bf_bits(v0.y);
        af[2] = f2bf_bits(v0.z); af[3] = f2bf_bits(v0.w);
        af[4] = f2bf_bits(v1.x); af[5] = f2bf_bits(v1.y);
        af[6] = f2bf_bits(v1.z); af[7] = f2bf_bits(v1.w);
      } else {
        af = *(const frag8*)((const bf16*)J.Av + (size_t)arow * K + k0);
      }
    } else {
#pragma unroll
      for (int j = 0; j < 8; j++) af[j] = 0;
    }
#pragma unroll
    for (int t = 0; t < 8; t++) {
      frag8 bfv = *(const frag8*)(Wt + (t * 16 + c) * stride + k0);
      acc[t] = __builtin_amdgcn_mfma_f32_16x16x32_bf16(af, bfv, acc[t], 0, 0, 0);
    }
    if (J.WT2) {
      frag8 b2 = *(const frag8*)(Wt2s + c * 136 + k0);
      acc2 = __builtin_amdgcn_mfma_f32_16x16x32_bf16(af, b2, acc2, 0, 0, 0);
    }
  }

  if (J.outFull) {
#pragma unroll
    for (int t = 0; t < 8; t++) {
#pragma unroll
      for (int r = 0; r < 4; r++) {
        int orow = mbase + quad * 4 + r;
        if (orow < J.M) {
          float v = acc[t][r];
          if (J.bias) v += J.bias[t * 16 + c];
          J.outFull[(size_t)orow * 128 + t * 16 + c] = __float2bfloat16(v);
        }
      }
    }
  }
  if (J.outScore) {
    const int H = J.H;
    const int TPH = 8 / H;
    for (int hh = 0; hh < H; hh++) {
#pragma unroll
      for (int r = 0; r < 4; r++) {
        float p = 0.f;
        for (int tt = 0; tt < TPH; tt++) {
          int t = hh * TPH + tt;
          p += acc[t][r] * J.avec[t * 16 + c];
        }
#pragma unroll
        for (int off = 1; off < 16; off <<= 1) p += __shfl_xor(p, off);
        int orow = mbase + quad * 4 + r;
        if (c == 0 && orow < J.M) J.outScore[(size_t)orow * H + hh] = p;
      }
    }
  }
  if (J.outScore2) {
#pragma unroll
    for (int r = 0; r < 4; r++) {
      int orow = mbase + quad * 4 + r;
      if (c < J.H2 && orow < J.M) J.outScore2[(size_t)orow * J.H2 + c] = acc2[r];
    }
  }
}

// ================= hist ∥ proj-GEMM (one dispatch) ==========================
__global__ __launch_bounds__(256) void histgemm_k(
    GemmJob ja, GemmJob jb, int gsplit,
    const int* __restrict__ dAB, const int* __restrict__ dBA, int E, int geh,
    int* __restrict__ cntB, int* __restrict__ cntA)
{
  const int b = blockIdx.x;
  if (b < 2 * geh) {
    if (b < geh) { int i = b * 256 + threadIdx.x; if (i < E) atomicAdd(&cntB[dAB[i]], 1); }
    else { int i = (b - geh) * 256 + threadIdx.x; if (i < E) atomicAdd(&cntA[dBA[i]], 1); }
    return;
  }
  const int gb = b - 2 * geh;
  if (gb < gsplit) gemm_body(ja, gb);
  else             gemm_body(jb, gb - gsplit);
}

// ================= parallel 3-stage scan (R2 structure) =====================
__device__ __forceinline__ void blocksum_body(const int* cnt, int N, int* bsum, int blk) {
  __shared__ int sh[256];
  const int tid = threadIdx.x;
  const int beg = blk * 1024;
  const int end = (beg + 1024 < N) ? beg + 1024 : N;
  int loc = 0;
  for (int i = beg + tid; i < end; i += 256) loc += cnt[i];
  sh[tid] = loc; __syncthreads();
  for (int off = 128; off; off >>= 1) { if (tid < off) sh[tid] += sh[tid + off]; __syncthreads(); }
  if (tid == 0) bsum[blk] = sh[0];
}
// blocksum ∥ layer-0 GEMM: per-block work of blocksum is tiny & parallel, so
// no straggler (unlike the R3 serial scanfull fusion which cost 131 us).
__global__ __launch_bounds__(256) void bsumgemm_k(
    GemmJob ja, GemmJob jb, int gsplit,
    const int* __restrict__ cntB, int NB, int* __restrict__ bsumB, int nbB,
    const int* __restrict__ cntA, int NA, int* __restrict__ bsumA, int nbA)
{
  const int b = blockIdx.x;
  if (b < nbB + nbA) {
    if (b < nbB) blocksum_body(cntB, NB, bsumB, b);
    else         blocksum_body(cntA, NA, bsumA, b - nbB);
    return;
  }
  const int gb = b - (nbB + nbA);
  if (gb < gsplit) gemm_body(ja, gb);
  else             gemm_body(jb, gb - gsplit);
}
__device__ __forceinline__ void scanpart_body(int* bsum, int nb) {
  __shared__ int sh[256];
  const int tid = threadIdx.x;
  int v = (tid < nb) ? bsum[tid] : 0;
  sh[tid] = v; __syncthreads();
  for (int off = 1; off < 256; off <<= 1) {
    int x = sh[tid];
    int o = (tid >= off) ? sh[tid - off] : 0;
    __syncthreads();
    sh[tid] = x + o;
    __syncthreads();
  }
  if (tid < nb) bsum[tid] = (tid == 0) ? 0 : sh[tid - 1];
}
__global__ void scanpart2_k(int* __restrict__ bsumB, int nbB, int* __restrict__ bsumA, int nbA) {
  if (blockIdx.x == 0) scanpart_body(bsumB, nbB);
  else                 scanpart_body(bsumA, nbA);
}
__device__ __forceinline__ void writerp_body(const int* cnt, int N, const int* bsum,
                                             int* rp, int* cur, int blk) {
  __shared__ int sh[256];
  const int tid = threadIdx.x;
  const int idx0 = blk * 1024 + tid * 4;
  int c[4]; int loc = 0;
#pragma unroll
  for (int j = 0; j < 4; j++) {
    int i = idx0 + j;
    c[j] = (i < N) ? cnt[i] : 0;
    loc += c[j];
  }
  sh[tid] = loc; __syncthreads();
  for (int off = 1; off < 256; off <<= 1) {
    int x = sh[tid];
    int o = (tid >= off) ? sh[tid - off] : 0;
    __syncthreads();
    sh[tid] = x + o;
    __syncthreads();
  }
  int run = bsum[blk] + ((tid == 0) ? 0 : sh[tid - 1]);
#pragma unroll
  for (int j = 0; j < 4; j++) {
    int i = idx0 + j;
    if (i < N) { rp[i] = run; cur[i] = run; }
    run += c[j];
  }
  if (idx0 <= N - 1 && N - 1 < idx0 + 4) rp[N] = run;  // total
}
__global__ void writerp2_k(const int* __restrict__ cntB, int NB, const int* __restrict__ bsumB,
                           int* __restrict__ rpAB, int* __restrict__ curB, int nbB,
                           const int* __restrict__ cntA, int NA, const int* __restrict__ bsumA,
                           int* __restrict__ rpBA, int* __restrict__ curA) {
  int b = blockIdx.x;
  if (b < nbB) writerp_body(cntB, NB, bsumB, rpAB, curB, b);
  else         writerp_body(cntA, NA, bsumA, rpBA, curA, b - nbB);
}

// plain dual-GEMM dispatch (layer 1)
__global__ __launch_bounds__(256) void gemm2_k(GemmJob ja, GemmJob jb, int split) {
  if (blockIdx.x < split) gemm_body(ja, blockIdx.x);
  else                    gemm_body(jb, blockIdx.x - split);
}

// ================= XCD-partitioned scatter ==================================
// 8 block-groups (blockIdx%8 ~ XCD); each group owns a disjoint dst range so
// cur[] atomics and sl[] lines stay XCD-local (kills cross-XCD write thrash).
// Correctness does NOT depend on the blockIdx->XCD mapping, only locality.
__global__ __launch_bounds__(256) void scatter8_k(
    const int* __restrict__ sAB, const int* __restrict__ dAB,
    const int* __restrict__ sBA, const int* __restrict__ dBA, int E,
    int* __restrict__ curB, int* __restrict__ slAB,
    int* __restrict__ curA, int* __restrict__ slBA, int NB, int NA)
{
  const int g = blockIdx.x & 7;
  const int sidx = blockIdx.x >> 3;
  const int loB = (int)((long long)NB * g >> 3), hiB = (int)((long long)NB * (g + 1) >> 3);
  const int loA = (int)((long long)NA * g >> 3), hiA = (int)((long long)NA * (g + 1) >> 3);
  const int b0 = sidx * 2048;
#pragma unroll
  for (int j = 0; j < 8; j++) {
    int i = b0 + j * 256 + threadIdx.x;
    if (i < 2 * E) {
      bool ab = i < E;
      int k = ab ? i : i - E;
      int d = ab ? dAB[k] : dBA[k];
      int lo = ab ? loB : loA, hi = ab ? hiB : hiA;
      if (d >= lo && d < hi) {
        int sv = ab ? sAB[k] : sBA[k];
        int pos = atomicAdd((ab ? curB : curA) + d, 1);
        (ab ? slAB : slBA)[pos] = sv;
      }
    }
  }
}

// ================= GAT aggregate ============================================
struct AggJob {
  const int* rp; const int* srcl; const float* as_; const float* ad_;
  const bf16* hs; const float* bias; const float* gamma; const float* beta;
  const bf16* resid; bf16* outBf; void* outFinal; const int* flagp;
  int nodeBase, N;
};

template<bool FINAL>
__device__ __forceinline__ void agg_epilogue(const AggJob& J, int n, int lane,
                                             float inv, float acc0, float acc1) {
  float2 bi = *(const float2*)(J.bias + 2 * lane);
  float y0 = acc0 * inv + bi.x;
  float y1 = acc1 * inv + bi.y;
  float tsum = wred_sum(y0 + y1);
  float tsq  = wred_sum(y0 * y0 + y1 * y1);
  float mu = tsum * 0.0078125f;
  float var = tsq * 0.0078125f - mu * mu;
  float rs = rsqrtf(var + 1e-5f);
  float2 ga = *(const float2*)(J.gamma + 2 * lane);
  float2 be = *(const float2*)(J.beta + 2 * lane);
  float z0 = (y0 - mu) * rs * ga.x + be.x;
  float z1 = (y1 - mu) * rs * ga.y + be.y;
  unsigned ru = *(const unsigned*)(J.resid + (size_t)n * 128 + 2 * lane);
  z0 = fmaxf(z0, 0.f) + bfbits2f((unsigned short)(ru & 0xFFFF));
  z1 = fmaxf(z1, 0.f) + bfbits2f((unsigned short)(ru >> 16));
  if constexpr (FINAL) {
    size_t oi = (size_t)(J.nodeBase + n) * 128 + 2 * lane;
    if (J.flagp[0]) {
      *(float2*)((float*)J.outFinal + oi) = make_float2(z0, z1);
    } else {
      unsigned short l0 = (unsigned short)f2bf_bits(z0);
      unsigned short l1 = (unsigned short)f2bf_bits(z1);
      *(unsigned*)((bf16*)J.outFinal + oi) = (unsigned)l0 | ((unsigned)l1 << 16);
    }
  } else {
    unsigned short l0 = (unsigned short)f2bf_bits(z0);
    unsigned short l1 = (unsigned short)f2bf_bits(z1);
    *(unsigned*)(J.outBf + (size_t)n * 128 + 2 * lane) = (unsigned)l0 | ((unsigned)l1 << 16);
  }
}

// H=4: phase-1 LDS p-staging (parallel exp); inner loop with readfirstlane'd
// wave/src so addressing is SALU and the gather uses an SGPR base.
template<bool FINAL>
__global__ __launch_bounds__(256) void agg4_k(AggJob JA, AggJob JB, int split) {
  const bool first = blockIdx.x < split;
  const AggJob J = first ? JA : JB;
  const int blk = first ? blockIdx.x : blockIdx.x - split;

  __shared__ float s_p[4][64 * 4];
  const int lane = threadIdx.x & 63;
  const int wave = __builtin_amdgcn_readfirstlane(threadIdx.x >> 6);
  const int n = blk * 4 + wave;                // uniform
  if (n >= J.N) return;

  const int beg = __builtin_amdgcn_readfirstlane(J.rp[n]);
  const int end = __builtin_amdgcn_readfirstlane(J.rp[n + 1]);
  const int myh = lane >> 4;
  const float4 adv = *(const float4*)(J.ad_ + (size_t)n * 4);
  float sl0 = 0.f, sl1 = 0.f, sl2 = 0.f, sl3 = 0.f;
  float acc0 = 0.f, acc1 = 0.f;
  const int* srcp = J.srcl;
  const bf16* hsp = J.hs;

  for (int base = beg; base < end; base += 64) {
    const int cn = (end - base < 64) ? end - base : 64;
    if (lane < cn) {
      int s = srcp[base + lane];
      float4 a = *(const float4*)(J.as_ + (size_t)s * 4);
      float4 o; float v;
      v = a.x + adv.x; v = v > 0.f ? v : 0.2f * v; o.x = __expf(v);
      v = a.y + adv.y; v = v > 0.f ? v : 0.2f * v; o.y = __expf(v);
      v = a.z + adv.z; v = v > 0.f ? v : 0.2f * v; o.z = __expf(v);
      v = a.w + adv.w; v = v > 0.f ? v : 0.2f * v; o.w = __expf(v);
      *(float4*)&s_p[wave][lane * 4] = o;
      sl0 += o.x; sl1 += o.y; sl2 += o.z; sl3 += o.w;
    }
    __builtin_amdgcn_wave_barrier();
#pragma unroll 4
    for (int e = 0; e < cn; e++) {
      const int src = __builtin_amdgcn_readfirstlane(srcp[base + e]);
      const float p = s_p[wave][e * 4 + myh];
      const unsigned u = *(const unsigned*)(hsp + (size_t)src * 128 + 2 * lane);
      acc0 += p * bfbits2f((unsigned short)(u & 0xFFFF));
      acc1 += p * bfbits2f((unsigned short)(u >> 16));
    }
    __builtin_amdgcn_wave_barrier();
  }

  float t0 = wred_sum(sl0), t1 = wred_sum(sl1), t2 = wred_sum(sl2), t3 = wred_sum(sl3);
  float s = (myh == 0) ? t0 : (myh == 1) ? t1 : (myh == 2) ? t2 : t3;
  const float inv = 1.f / (s + 1e-16f);
  agg_epilogue<FINAL>(J, n, lane, inv, acc0, acc1);
}

// H=1: fully scalar edge loop — src/as via uniform loads, p computed inline
// (no LDS, no barriers, softmax denom uniform so no reduction).
template<bool FINAL>
__global__ __launch_bounds__(256) void agg1_k(AggJob JA, AggJob JB, int split) {
  const bool first = blockIdx.x < split;
  const AggJob J = first ? JA : JB;
  const int blk = first ? blockIdx.x : blockIdx.x - split;

  const int lane = threadIdx.x & 63;
  const int wave = __builtin_amdgcn_readfirstlane(threadIdx.x >> 6);
  const int n = blk * 4 + wave;                // uniform
  if (n >= J.N) return;

  const int beg = __builtin_amdgcn_readfirstlane(J.rp[n]);
  const int end = __builtin_amdgcn_readfirstlane(J.rp[n + 1]);
  const float adn = rfl_f(J.ad_[n]);
  float sum = 0.f, acc0 = 0.f, acc1 = 0.f;
  const int* srcp = J.srcl;
  const float* asp = J.as_;
  const bf16* hsp = J.hs;

#pragma unroll 4
  for (int e = beg; e < end; e++) {
    const int src = __builtin_amdgcn_readfirstlane(srcp[e]);
    float v = rfl_f(asp[src]) + adn;
    v = v > 0.f ? v : 0.2f * v;
    const float p = __expf(v);
    sum += p;
    const unsigned u = *(const unsigned*)(hsp + (size_t)src * 128 + 2 * lane);
    acc0 += p * bfbits2f((unsigned short)(u & 0xFFFF));
    acc1 += p * bfbits2f((unsigned short)(u >> 16));
  }
  const float inv = 1.f / (sum + 1e-16f);
  agg_epilogue<FINAL>(J, n, lane, inv, acc0, acc1);
}

extern "C" void kernel_launch(void* const* d_in, const int* in_sizes, int n_in,
                              void* d_out, int out_size, void* d_ws, size_t ws_size,
                              hipStream_t stream)
{
  const int NA = in_sizes[0] / 128;
  const int NB = in_sizes[1] / 64;
  const int E  = in_sizes[30] / 2;
  const int* eiAB = (const int*)d_in[30];
  const int* eiBA = (const int*)d_in[31];
  const int* srcAB = eiAB;  const int* dstAB = eiAB + E;
  const int* srcBA = eiBA;  const int* dstBA = eiBA + E;

  char* w = (char*)d_ws;
  size_t used = 0;
  auto alloc = [&](size_t bytes) {
    char* p = w + used;
    used += (bytes + 255) & ~size_t(255);
    return (void*)p;
  };
  int*  flag  = (int*)alloc(256);
  bf16* WcA   = (bf16*)alloc(16384 * 2);
  bf16* WcB   = (bf16*)alloc(8192 * 2);
  bf16* Wc0ab = (bf16*)alloc(16384 * 2);
  bf16* Wc0ba = (bf16*)alloc(16384 * 2);
  bf16* Wc1ab = (bf16*)alloc(16384 * 2);
  bf16* Wc1ba = (bf16*)alloc(16384 * 2);
  bf16* Wt0ab = (bf16*)alloc(16 * 128 * 2);    // folded W*ad tiles
  bf16* Wt0ba = (bf16*)alloc(16 * 128 * 2);
  bf16* Wt1ab = (bf16*)alloc(16 * 128 * 2);
  bf16* Wt1ba = (bf16*)alloc(16 * 128 * 2);
  float* vec  = (float*)alloc(22 * 128 * 4);
  bf16* hA    = (bf16*)alloc((size_t)NA * 128 * 2);
  bf16* hB    = (bf16*)alloc((size_t)NB * 128 * 2);
  bf16* hsAB  = (bf16*)alloc((size_t)NA * 128 * 2);
  bf16* hsBA  = (bf16*)alloc((size_t)NB * 128 * 2);
  float* asAB = (float*)alloc((size_t)NA * 4 * 4);
  float* adAB = (float*)alloc((size_t)NB * 4 * 4);
  float* asBA = (float*)alloc((size_t)NB * 4 * 4);
  float* adBA = (float*)alloc((size_t)NA * 4 * 4);
  int* rpAB = (int*)alloc((size_t)(NB + 1) * 4);
  int* slAB = (int*)alloc((size_t)E * 4);
  int* rpBA = (int*)alloc((size_t)(NA + 1) * 4);
  int* slBA = (int*)alloc((size_t)E * 4);
  int* cntA = (int*)alloc((size_t)NA * 4);
  int* curA = (int*)alloc((size_t)NA * 4);
  int* cntB = (int*)alloc((size_t)NB * 4);
  int* curB = (int*)alloc((size_t)NB * 4);
  int* bsumA = (int*)alloc(256 * 4);
  int* bsumB = (int*)alloc(256 * 4);
  if (used > ws_size) return;  // diagnostic: absmax would equal max|ref| (~6.84)

  auto V = [&](int i) { return vec + 128 * i; };
  // vec slots: 0 pbA, 1 pbB, 2 as0ab, 3 ad0ab, 4 b0ab, 5 as0ba, 6 ad0ba,
  // 7 b0ba, 8 as1ab, 9 ad1ab, 10 b1ab, 11 as1ba, 12 ad1ba, 13 b1ba,
  // 14 g0A, 15 bn0A, 16 g0B, 17 bn0B, 18 g1A, 19 bn1A, 20 g1B, 21 bn1B

  ConvJobs jobs{};
  int nj = 0;
  auto addT = [&](const void* s, void* d, int K) {
    int ksh = (K == 128) ? 7 : 6;
    jobs.j[nj++] = ConvJob{s, d, 128 * K, 1, ksh};
  };
  auto addV = [&](const void* s, void* d) { jobs.j[nj++] = ConvJob{s, d, 128, 0, 7}; };
  addT(d_in[2], WcA, 128);
  addT(d_in[4], WcB, 64);
  addT(d_in[6], Wc0ab, 128);
  addT(d_in[10], Wc0ba, 128);
  addT(d_in[14], Wc1ab, 128);
  addT(d_in[18], Wc1ba, 128);
  const int vsrc[22] = {3, 5, 7, 8, 9, 11, 12, 13, 15, 16, 17, 19, 20, 21, 22, 23, 24, 25, 26, 27, 28, 29};
  for (int i = 0; i < 22; i++) addV(d_in[vsrc[i]], V(i));

  WtJobs4 wj{};
  wj.j[0] = WtJob{d_in[6],  d_in[8],  Wt0ab, 4};
  wj.j[1] = WtJob{d_in[10], d_in[12], Wt0ba, 4};
  wj.j[2] = WtJob{d_in[14], d_in[16], Wt1ab, 1};
  wj.j[3] = WtJob{d_in[18], d_in[20], Wt1ba, 1};

  const int nz = (NA + NB + 255) / 256;
  // D1: prep (flag, canonicalize, wtilde, cnt zero)
  prep_k<<<nj + 4 + nz, 256, 0, stream>>>((const unsigned*)d_in[0], flag, jobs, nj, wj,
                                          cntA, NA, cntB, NB);

  const int geh = (E + 255) / 256;
  const int gA = (NA + 63) / 64, gB = (NB + 63) / 64;
  const int aA = (NA + 3) / 4, aB = (NB + 3) / 4;
  const int nbB = (NB + 1023) / 1024, nbA = (NA + 1023) / 1024;

  // D2: hist (both dirs) ∥ input-projection GEMMs
  {
    GemmJob ja{d_in[0], WcA, V(0), nullptr, hA, nullptr, flag, nullptr, nullptr, NA, 128, 1, 0};
    GemmJob jb{d_in[1], WcB, V(1), nullptr, hB, nullptr, flag, nullptr, nullptr, NB, 64, 1, 0};
    histgemm_k<<<2 * geh + gA + gB, 256, 0, stream>>>(ja, jb, gA, dstAB, dstBA, E, geh,
                                                      cntB, cntA);
  }
  // D3: blocksum (parallel, both dirs) ∥ layer-0 GEMMs
  {
    GemmJob ja{hA, Wc0ab, nullptr, V(2), hsAB, asAB, nullptr, Wt0ba, adBA, NA, 128, 4, 4};
    GemmJob jb{hB, Wc0ba, nullptr, V(5), hsBA, asBA, nullptr, Wt0ab, adAB, NB, 128, 4, 4};
    bsumgemm_k<<<nbB + nbA + gA + gB, 256, 0, stream>>>(ja, jb, gA,
                                                        cntB, NB, bsumB, nbB,
                                                        cntA, NA, bsumA, nbA);
  }
  // D4: scan partials (2 tiny blocks)
  scanpart2_k<<<2, 256, 0, stream>>>(bsumB, nbB, bsumA, nbA);
  // D5: write row pointers
  writerp2_k<<<nbB + nbA, 256, 0, stream>>>(cntB, NB, bsumB, rpAB, curB, nbB,
                                            cntA, NA, bsumA, rpBA, curA);
  // D6: XCD-partitioned scatter (both dirs)
  {
    const int nsl = (2 * E + 2047) / 2048;
    scatter8_k<<<8 * nsl, 256, 0, stream>>>(srcAB, dstAB, srcBA, dstBA, E,
                                            curB, slAB, curA, slBA, NB, NA);
  }
  // D7: layer-0 aggregate (H=4, both dirs)
  {
    AggJob ja{rpAB, slAB, asAB, adAB, hsAB, V(4), V(16), V(17), hB, hB, nullptr, nullptr, 0, NB};
    AggJob jb{rpBA, slBA, asBA, adBA, hsBA, V(7), V(14), V(15), hA, hA, nullptr, nullptr, 0, NA};
    agg4_k<false><<<aB + aA, 256, 0, stream>>>(ja, jb, aB);
  }
  // D8: layer-1 GEMMs
  {
    GemmJob ja{hA, Wc1ab, nullptr, V(8),  hsAB, asAB, nullptr, Wt1ba, adBA, NA, 128, 1, 1};
    GemmJob jb{hB, Wc1ba, nullptr, V(11), hsBA, asBA, nullptr, Wt1ab, adAB, NB, 128, 1, 1};
    gemm2_k<<<gA + gB, 256, 0, stream>>>(ja, jb, gA);
  }
  // D9: layer-1 aggregate (H=1, both dirs, final output)
  {
    AggJob ja{rpAB, slAB, asAB, adAB, hsAB, V(10), V(20), V(21), hB, nullptr, d_out, flag, NA, NB};
    AggJob jb{rpBA, slBA, asBA, adBA, hsBA, V(13), V(18), V(19), hA, nullptr, d_out, flag, 0, NA};
    agg1_k<true><<<aB + aA, 256, 0, stream>>>(ja, jb, aB);
  }
}

// Round 5
// 467.407 us; speedup vs baseline: 1.2659x; 1.0817x over previous
//
#include <hip/hip_runtime.h>
#include <hip/hip_bf16.h>

using bf16 = __hip_bfloat16;
using frag8 = __attribute__((ext_vector_type(8))) short;  // 8 bf16 (4 VGPRs)
using f32x4 = __attribute__((ext_vector_type(4))) float;  // MFMA C/D

__device__ __forceinline__ short f2bf_bits(float f) {
  bf16 h = __float2bfloat16(f);
  short s; __builtin_memcpy(&s, &h, 2); return s;
}
__device__ __forceinline__ float bfbits2f(unsigned short u) {
  unsigned uu = (unsigned)u << 16; float f; __builtin_memcpy(&f, &uu, 4); return f;
}
__device__ __forceinline__ float wred_sum(float v) {
#pragma unroll
  for (int o = 32; o; o >>= 1) v += __shfl_xor(v, o);
  return v;
}

// ================= prep: flag-detect + param canonicalize + wtilde fold +
// cnt zeroing, all in ONE dispatch (each block self-detects the dtype flag
// from the first 16KB of x_A).
struct ConvJob { const void* src; void* dst; int n; int mode; int ksh; };
struct ConvJobs { ConvJob j[28]; };
struct WtJob { const void* wraw; const void* adraw; bf16* out; int H; };
struct WtJobs4 { WtJob j[4]; };

__global__ __launch_bounds__(256) void prep_k(
    const unsigned* __restrict__ xdet, int* __restrict__ flag,
    ConvJobs cjobs, int ncv, WtJobs4 wjobs,
    int* __restrict__ cntA, int nA, int* __restrict__ cntB, int nB)
{
  const int b = blockIdx.x, tid = threadIdx.x;
  if (b >= ncv + 4) {                         // cnt zero region (no flag needed)
    int i = (b - (ncv + 4)) * 256 + tid;
    if (i < nA) cntA[i] = 0;
    else if (i < nA + nB) cntB[i - nA] = 0;
    return;
  }
  __shared__ int sh[256];
  int c = 0;
  for (int i = tid; i < 4096; i += 256) {
    unsigned bb = (xdet[i] >> 8) & 0x7F;
    c += (bb >= 0x3B && bb <= 0x41) ? 1 : 0;
  }
  sh[tid] = c; __syncthreads();
  for (int off = 128; off; off >>= 1) { if (tid < off) sh[tid] += sh[tid + off]; __syncthreads(); }
  const int f = (sh[0] < 2048) ? 1 : 0;
  if (b == 0 && tid == 0) flag[0] = f;

  if (b < ncv) {                              // canonicalize job
    ConvJob J = cjobs.j[b];
    const int Kt = 1 << J.ksh;
    for (int i = tid; i < J.n; i += 256) {
      int si = i;
      if (J.mode == 1) { int n = i >> J.ksh, k = i & (Kt - 1); si = k * 128 + n; }
      float v = f ? ((const float*)J.src)[si] : bfbits2f(((const unsigned short*)J.src)[si]);
      if (J.mode == 1) ((bf16*)J.dst)[i] = __float2bfloat16(v);
      else             ((float*)J.dst)[i] = v;
    }
  } else {                                    // wtilde fold from RAW W and ad
    WtJob J = wjobs.j[b - ncv];               // Wt2[h][k] = sum_d W[k][h*D+d]*ad[h*D+d]
    const int H = J.H, D = 128 / H;
    for (int idx = tid; idx < 16 * 128; idx += 256) {
      int h = idx >> 7, k = idx & 127;
      float s = 0.f;
      if (h < H) {
        for (int d = 0; d < D; d++) {
          int n = h * D + d;
          float wv = f ? ((const float*)J.wraw)[k * 128 + n]
                       : bfbits2f(((const unsigned short*)J.wraw)[k * 128 + n]);
          float av = f ? ((const float*)J.adraw)[n]
                       : bfbits2f(((const unsigned short*)J.adraw)[n]);
          s += wv * av;
        }
      }
      J.out[idx] = __float2bfloat16(s);
    }
  }
}

// ================= GEMM body (shared by merged kernels) =====================
struct GemmJob {
  const void* Av; const bf16* WT; const float* bias; const float* avec;
  bf16* outFull; float* outScore; const int* flagp;
  const bf16* WT2; float* outScore2;
  int M, K, H, H2;
};
__device__ __forceinline__ void gemm_body(const GemmJob& J, int blk) {
  __shared__ __align__(16) bf16 Wt[128 * 136];
  __shared__ __align__(16) bf16 Wt2s[16 * 136];
  const int tid = threadIdx.x;
  const int K = J.K;
  const int isf32 = J.flagp ? J.flagp[0] : 0;
  const int stride = K + 8;
  const int ksh2 = (K == 128) ? 4 : 3;
  const int kunits = K >> 3;
  for (int u = tid; u < 128 * kunits; u += 256) {
    int n = u >> ksh2, kb = u & (kunits - 1);
    frag8 v = *(const frag8*)(J.WT + n * K + kb * 8);
    *(frag8*)(Wt + n * stride + kb * 8) = v;
  }
  if (J.WT2) {
    int n = tid >> 4, kb = tid & 15;
    *(frag8*)(Wt2s + n * 136 + kb * 8) = *(const frag8*)(J.WT2 + n * 128 + kb * 8);
  }
  __syncthreads();

  const int lane = tid & 63, wave = tid >> 6;
  const int quad = lane >> 4, c = lane & 15;
  const int mbase = blk * 64 + wave * 16;
  const int arow = mbase + c;
  const bool rowOK = arow < J.M;

  f32x4 acc[8];
#pragma unroll
  for (int t = 0; t < 8; t++) acc[t] = (f32x4){0.f, 0.f, 0.f, 0.f};
  f32x4 acc2 = (f32x4){0.f, 0.f, 0.f, 0.f};

  for (int ks = 0; ks < K; ks += 32) {
    frag8 af;
    const int k0 = ks + quad * 8;
    if (rowOK) {
      if (isf32) {
        const float4* ap = (const float4*)((const float*)J.Av + (size_t)arow * K + k0);
        float4 v0 = ap[0], v1 = ap[1];
        af[0] = f2bf_bits(v0.x); af[1] = f2bf_bits(v0.y);
        af[2] = f2bf_bits(v0.z); af[3] = f2bf_bits(v0.w);
        af[4] = f2bf_bits(v1.x); af[5] = f2bf_bits(v1.y);
        af[6] = f2bf_bits(v1.z); af[7] = f2bf_bits(v1.w);
      } else {
        af = *(const frag8*)((const bf16*)J.Av + (size_t)arow * K + k0);
      }
    } else {
#pragma unroll
      for (int j = 0; j < 8; j++) af[j] = 0;
    }
#pragma unroll
    for (int t = 0; t < 8; t++) {
      frag8 bfv = *(const frag8*)(Wt + (t * 16 + c) * stride + k0);
      acc[t] = __builtin_amdgcn_mfma_f32_16x16x32_bf16(af, bfv, acc[t], 0, 0, 0);
    }
    if (J.WT2) {
      frag8 b2 = *(const frag8*)(Wt2s + c * 136 + k0);
      acc2 = __builtin_amdgcn_mfma_f32_16x16x32_bf16(af, b2, acc2, 0, 0, 0);
    }
  }

  if (J.outFull) {
#pragma unroll
    for (int t = 0; t < 8; t++) {
#pragma unroll
      for (int r = 0; r < 4; r++) {
        int orow = mbase + quad * 4 + r;
        if (orow < J.M) {
          float v = acc[t][r];
          if (J.bias) v += J.bias[t * 16 + c];
          J.outFull[(size_t)orow * 128 + t * 16 + c] = __float2bfloat16(v);
        }
      }
    }
  }
  if (J.outScore) {
    const int H = J.H;
    const int TPH = 8 / H;
    for (int hh = 0; hh < H; hh++) {
#pragma unroll
      for (int r = 0; r < 4; r++) {
        float p = 0.f;
        for (int tt = 0; tt < TPH; tt++) {
          int t = hh * TPH + tt;
          p += acc[t][r] * J.avec[t * 16 + c];
        }
#pragma unroll
        for (int off = 1; off < 16; off <<= 1) p += __shfl_xor(p, off);
        int orow = mbase + quad * 4 + r;
        if (c == 0 && orow < J.M) J.outScore[(size_t)orow * H + hh] = p;
      }
    }
  }
  if (J.outScore2) {
#pragma unroll
    for (int r = 0; r < 4; r++) {
      int orow = mbase + quad * 4 + r;
      if (c < J.H2 && orow < J.M) J.outScore2[(size_t)orow * J.H2 + c] = acc2[r];
    }
  }
}

// ================= hist ∥ proj-GEMM (one dispatch) ==========================
__global__ __launch_bounds__(256) void histgemm_k(
    GemmJob ja, GemmJob jb, int gsplit,
    const int* __restrict__ dAB, const int* __restrict__ dBA, int E, int geh,
    int* __restrict__ cntB, int* __restrict__ cntA)
{
  const int b = blockIdx.x;
  if (b < 2 * geh) {
    if (b < geh) { int i = b * 256 + threadIdx.x; if (i < E) atomicAdd(&cntB[dAB[i]], 1); }
    else { int i = (b - geh) * 256 + threadIdx.x; if (i < E) atomicAdd(&cntA[dBA[i]], 1); }
    return;
  }
  const int gb = b - 2 * geh;
  if (gb < gsplit) gemm_body(ja, gb);
  else             gemm_body(jb, gb - gsplit);
}

// ================= parallel 3-stage scan ====================================
__device__ __forceinline__ void blocksum_body(const int* cnt, int N, int* bsum, int blk) {
  __shared__ int sh[256];
  const int tid = threadIdx.x;
  const int beg = blk * 1024;
  const int end = (beg + 1024 < N) ? beg + 1024 : N;
  int loc = 0;
  for (int i = beg + tid; i < end; i += 256) loc += cnt[i];
  sh[tid] = loc; __syncthreads();
  for (int off = 128; off; off >>= 1) { if (tid < off) sh[tid] += sh[tid + off]; __syncthreads(); }
  if (tid == 0) bsum[blk] = sh[0];
}
__global__ __launch_bounds__(256) void bsumgemm_k(
    GemmJob ja, GemmJob jb, int gsplit,
    const int* __restrict__ cntB, int NB, int* __restrict__ bsumB, int nbB,
    const int* __restrict__ cntA, int NA, int* __restrict__ bsumA, int nbA)
{
  const int b = blockIdx.x;
  if (b < nbB + nbA) {
    if (b < nbB) blocksum_body(cntB, NB, bsumB, b);
    else         blocksum_body(cntA, NA, bsumA, b - nbB);
    return;
  }
  const int gb = b - (nbB + nbA);
  if (gb < gsplit) gemm_body(ja, gb);
  else             gemm_body(jb, gb - gsplit);
}
__device__ __forceinline__ void scanpart_body(int* bsum, int nb) {
  __shared__ int sh[256];
  const int tid = threadIdx.x;
  int v = (tid < nb) ? bsum[tid] : 0;
  sh[tid] = v; __syncthreads();
  for (int off = 1; off < 256; off <<= 1) {
    int x = sh[tid];
    int o = (tid >= off) ? sh[tid - off] : 0;
    __syncthreads();
    sh[tid] = x + o;
    __syncthreads();
  }
  if (tid < nb) bsum[tid] = (tid == 0) ? 0 : sh[tid - 1];
}
__global__ void scanpart2_k(int* __restrict__ bsumB, int nbB, int* __restrict__ bsumA, int nbA) {
  if (blockIdx.x == 0) scanpart_body(bsumB, nbB);
  else                 scanpart_body(bsumA, nbA);
}
__device__ __forceinline__ void writerp_body(const int* cnt, int N, const int* bsum,
                                             int* rp, int* cur, int blk) {
  __shared__ int sh[256];
  const int tid = threadIdx.x;
  const int idx0 = blk * 1024 + tid * 4;
  int c[4]; int loc = 0;
#pragma unroll
  for (int j = 0; j < 4; j++) {
    int i = idx0 + j;
    c[j] = (i < N) ? cnt[i] : 0;
    loc += c[j];
  }
  sh[tid] = loc; __syncthreads();
  for (int off = 1; off < 256; off <<= 1) {
    int x = sh[tid];
    int o = (tid >= off) ? sh[tid - off] : 0;
    __syncthreads();
    sh[tid] = x + o;
    __syncthreads();
  }
  int run = bsum[blk] + ((tid == 0) ? 0 : sh[tid - 1]);
#pragma unroll
  for (int j = 0; j < 4; j++) {
    int i = idx0 + j;
    if (i < N) { rp[i] = run; cur[i] = run; }
    run += c[j];
  }
  if (idx0 <= N - 1 && N - 1 < idx0 + 4) rp[N] = run;  // total
}
__global__ void writerp2_k(const int* __restrict__ cntB, int NB, const int* __restrict__ bsumB,
                           int* __restrict__ rpAB, int* __restrict__ curB, int nbB,
                           const int* __restrict__ cntA, int NA, const int* __restrict__ bsumA,
                           int* __restrict__ rpBA, int* __restrict__ curA) {
  int b = blockIdx.x;
  if (b < nbB) writerp_body(cntB, NB, bsumB, rpAB, curB, b);
  else         writerp_body(cntA, NA, bsumA, rpBA, curA, b - nbB);
}

// plain dual-GEMM dispatch (layer 1)
__global__ __launch_bounds__(256) void gemm2_k(GemmJob ja, GemmJob jb, int split) {
  if (blockIdx.x < split) gemm_body(ja, blockIdx.x);
  else                    gemm_body(jb, blockIdx.x - split);
}

// ================= XCD-partitioned scatter ==================================
__global__ __launch_bounds__(256) void scatter8_k(
    const int* __restrict__ sAB, const int* __restrict__ dAB,
    const int* __restrict__ sBA, const int* __restrict__ dBA, int E,
    int* __restrict__ curB, int* __restrict__ slAB,
    int* __restrict__ curA, int* __restrict__ slBA, int NB, int NA)
{
  const int g = blockIdx.x & 7;
  const int sidx = blockIdx.x >> 3;
  const int loB = (int)((long long)NB * g >> 3), hiB = (int)((long long)NB * (g + 1) >> 3);
  const int loA = (int)((long long)NA * g >> 3), hiA = (int)((long long)NA * (g + 1) >> 3);
  const int b0 = sidx * 2048;
#pragma unroll
  for (int j = 0; j < 8; j++) {
    int i = b0 + j * 256 + threadIdx.x;
    if (i < 2 * E) {
      bool ab = i < E;
      int k = ab ? i : i - E;
      int d = ab ? dAB[k] : dBA[k];
      int lo = ab ? loB : loA, hi = ab ? hiB : hiA;
      if (d >= lo && d < hi) {
        int sv = ab ? sAB[k] : sBA[k];
        int pos = atomicAdd((ab ? curB : curA) + d, 1);
        (ab ? slAB : slBA)[pos] = sv;
      }
    }
  }
}

// ================= GAT aggregate (dual-edge: 2 edges per wave-instr) ========
// One wave per node. Phase 1: 64 edges staged — coalesced src load, as-gather,
// p = exp(leaky(as[src]+ad[n])) to LDS, per-lane denom partials. Phase 2:
// lanes 0-31 process edge e, lanes 32-63 edge e+1; each lane loads uint2
// (4 dims, 8B) -> 512B per wave-instr, unroll 4 => 8 edges in flight.
// Combine halves via shfl_xor(32). Epilogue: 4 dims/lane (halves duplicated,
// LN sums scaled by 1/256), writes gated to half 0.
struct AggJob {
  const int* rp; const int* srcl; const float* as_; const float* ad_;
  const bf16* hs; const float* bias; const float* gamma; const float* beta;
  const bf16* resid; bf16* outBf; void* outFinal; const int* flagp;
  int nodeBase, N;
};

template<bool FINAL>
__device__ __forceinline__ void agg_epi4(const AggJob& J, int n, int hl, int half,
                                         float inv, float a0, float a1, float a2, float a3) {
  float4 bi = *(const float4*)(J.bias + 4 * hl);
  float y0 = a0 * inv + bi.x;
  float y1 = a1 * inv + bi.y;
  float y2 = a2 * inv + bi.z;
  float y3 = a3 * inv + bi.w;
  float tsum = wred_sum(y0 + y1 + y2 + y3);          // halves duplicated: 2x
  float tsq  = wred_sum(y0 * y0 + y1 * y1 + y2 * y2 + y3 * y3);
  float mu = tsum * 0.00390625f;                     // 1/256
  float var = tsq * 0.00390625f - mu * mu;
  float rs = rsqrtf(var + 1e-5f);
  float4 ga = *(const float4*)(J.gamma + 4 * hl);
  float4 be = *(const float4*)(J.beta + 4 * hl);
  float z0 = (y0 - mu) * rs * ga.x + be.x;
  float z1 = (y1 - mu) * rs * ga.y + be.y;
  float z2 = (y2 - mu) * rs * ga.z + be.z;
  float z3 = (y3 - mu) * rs * ga.w + be.w;
  uint2 ru = *(const uint2*)(J.resid + (size_t)n * 128 + hl * 4);
  z0 = fmaxf(z0, 0.f) + bfbits2f((unsigned short)(ru.x & 0xFFFF));
  z1 = fmaxf(z1, 0.f) + bfbits2f((unsigned short)(ru.x >> 16));
  z2 = fmaxf(z2, 0.f) + bfbits2f((unsigned short)(ru.y & 0xFFFF));
  z3 = fmaxf(z3, 0.f) + bfbits2f((unsigned short)(ru.y >> 16));
  if (half == 0) {
    if constexpr (FINAL) {
      size_t oi = (size_t)(J.nodeBase + n) * 128 + hl * 4;
      if (J.flagp[0]) {
        *(float4*)((float*)J.outFinal + oi) = make_float4(z0, z1, z2, z3);
      } else {
        uint2 pk;
        pk.x = (unsigned)(unsigned short)f2bf_bits(z0) | ((unsigned)(unsigned short)f2bf_bits(z1) << 16);
        pk.y = (unsigned)(unsigned short)f2bf_bits(z2) | ((unsigned)(unsigned short)f2bf_bits(z3) << 16);
        *(uint2*)((bf16*)J.outFinal + oi) = pk;
      }
    } else {
      uint2 pk;
      pk.x = (unsigned)(unsigned short)f2bf_bits(z0) | ((unsigned)(unsigned short)f2bf_bits(z1) << 16);
      pk.y = (unsigned)(unsigned short)f2bf_bits(z2) | ((unsigned)(unsigned short)f2bf_bits(z3) << 16);
      *(uint2*)(J.outBf + (size_t)n * 128 + hl * 4) = pk;
    }
  }
}

template<int H, bool FINAL>
__global__ __launch_bounds__(256) void agg_k(AggJob JA, AggJob JB, int split) {
  const bool first = blockIdx.x < split;
  const AggJob J = first ? JA : JB;
  const int blk = first ? blockIdx.x : blockIdx.x - split;

  __shared__ int   s_src[4][64];
  __shared__ float s_p[4][64 * H];
  const int tid = threadIdx.x;
  const int wave = tid >> 6, lane = tid & 63;
  const int n = blk * 4 + wave;
  if (n >= J.N) return;                        // no block barriers below

  const int beg = J.rp[n], end = J.rp[n + 1];
  const int half = lane >> 5;                  // which edge of the pair
  const int hl = lane & 31;                    // dim group: elems 4*hl..4*hl+3
  const int myh = (H == 4) ? (hl >> 3) : 0;

  float4 adv;
  if (H == 4) adv = *(const float4*)(J.ad_ + (size_t)n * 4);
  else        adv.x = J.ad_[n];

  float sl_[H];
#pragma unroll
  for (int h = 0; h < H; h++) sl_[h] = 0.f;
  float a0 = 0.f, a1 = 0.f, a2 = 0.f, a3 = 0.f;
  const int* srcp = J.srcl;
  const float* asp = J.as_;
  const bf16* hsp = J.hs;

  for (int base = beg; base < end; base += 64) {
    const int cn = (end - base < 64) ? end - base : 64;
    if (lane < cn) {
      int s = srcp[base + lane];
      s_src[wave][lane] = s;
      if (H == 4) {
        float4 a = *(const float4*)(asp + (size_t)s * 4);
        float4 o; float v;
        v = a.x + adv.x; v = v > 0.f ? v : 0.2f * v; o.x = __expf(v);
        v = a.y + adv.y; v = v > 0.f ? v : 0.2f * v; o.y = __expf(v);
        v = a.z + adv.z; v = v > 0.f ? v : 0.2f * v; o.z = __expf(v);
        v = a.w + adv.w; v = v > 0.f ? v : 0.2f * v; o.w = __expf(v);
        *(float4*)&s_p[wave][lane * 4] = o;
        sl_[0] += o.x; sl_[1] += o.y; sl_[2] += o.z; sl_[3] += o.w;
      } else {
        float v = asp[s] + adv.x;
        v = v > 0.f ? v : 0.2f * v;
        float pv = __expf(v);
        s_p[wave][lane] = pv;
        sl_[0] += pv;
      }
    }
    __builtin_amdgcn_wave_barrier();
    const int cne = cn & ~1;
#pragma unroll 4
    for (int e = 0; e < cne; e += 2) {
      const int eidx = e + half;
      const int s = s_src[wave][eidx];
      const float p = s_p[wave][eidx * H + myh];
      const uint2 u = *(const uint2*)(hsp + (size_t)s * 128 + hl * 4);
      a0 += p * bfbits2f((unsigned short)(u.x & 0xFFFF));
      a1 += p * bfbits2f((unsigned short)(u.x >> 16));
      a2 += p * bfbits2f((unsigned short)(u.y & 0xFFFF));
      a3 += p * bfbits2f((unsigned short)(u.y >> 16));
    }
    if (cn & 1) {                              // odd tail: half 1 contributes 0
      const int eidx = cn - 1;
      const int s = s_src[wave][eidx];
      const float p = half ? 0.f : s_p[wave][eidx * H + myh];
      const uint2 u = *(const uint2*)(hsp + (size_t)s * 128 + hl * 4);
      a0 += p * bfbits2f((unsigned short)(u.x & 0xFFFF));
      a1 += p * bfbits2f((unsigned short)(u.x >> 16));
      a2 += p * bfbits2f((unsigned short)(u.y & 0xFFFF));
      a3 += p * bfbits2f((unsigned short)(u.y >> 16));
    }
    __builtin_amdgcn_wave_barrier();
  }

  // combine the two half-wave edge partitions
  a0 += __shfl_xor(a0, 32);
  a1 += __shfl_xor(a1, 32);
  a2 += __shfl_xor(a2, 32);
  a3 += __shfl_xor(a3, 32);

  float s = 0.f;
#pragma unroll
  for (int h = 0; h < H; h++) {
    float t = wred_sum(sl_[h]);
    if (h == myh) s = t;
  }
  const float inv = 1.f / (s + 1e-16f);
  agg_epi4<FINAL>(J, n, hl, half, inv, a0, a1, a2, a3);
}

extern "C" void kernel_launch(void* const* d_in, const int* in_sizes, int n_in,
                              void* d_out, int out_size, void* d_ws, size_t ws_size,
                              hipStream_t stream)
{
  const int NA = in_sizes[0] / 128;
  const int NB = in_sizes[1] / 64;
  const int E  = in_sizes[30] / 2;
  const int* eiAB = (const int*)d_in[30];
  const int* eiBA = (const int*)d_in[31];
  const int* srcAB = eiAB;  const int* dstAB = eiAB + E;
  const int* srcBA = eiBA;  const int* dstBA = eiBA + E;

  char* w = (char*)d_ws;
  size_t used = 0;
  auto alloc = [&](size_t bytes) {
    char* p = w + used;
    used += (bytes + 255) & ~size_t(255);
    return (void*)p;
  };
  int*  flag  = (int*)alloc(256);
  bf16* WcA   = (bf16*)alloc(16384 * 2);
  bf16* WcB   = (bf16*)alloc(8192 * 2);
  bf16* Wc0ab = (bf16*)alloc(16384 * 2);
  bf16* Wc0ba = (bf16*)alloc(16384 * 2);
  bf16* Wc1ab = (bf16*)alloc(16384 * 2);
  bf16* Wc1ba = (bf16*)alloc(16384 * 2);
  bf16* Wt0ab = (bf16*)alloc(16 * 128 * 2);    // folded W*ad tiles
  bf16* Wt0ba = (bf16*)alloc(16 * 128 * 2);
  bf16* Wt1ab = (bf16*)alloc(16 * 128 * 2);
  bf16* Wt1ba = (bf16*)alloc(16 * 128 * 2);
  float* vec  = (float*)alloc(22 * 128 * 4);
  bf16* hA    = (bf16*)alloc((size_t)NA * 128 * 2);
  bf16* hB    = (bf16*)alloc((size_t)NB * 128 * 2);
  bf16* hsAB  = (bf16*)alloc((size_t)NA * 128 * 2);
  bf16* hsBA  = (bf16*)alloc((size_t)NB * 128 * 2);
  float* asAB = (float*)alloc((size_t)NA * 4 * 4);
  float* adAB = (float*)alloc((size_t)NB * 4 * 4);
  float* asBA = (float*)alloc((size_t)NB * 4 * 4);
  float* adBA = (float*)alloc((size_t)NA * 4 * 4);
  int* rpAB = (int*)alloc((size_t)(NB + 1) * 4);
  int* slAB = (int*)alloc((size_t)E * 4);
  int* rpBA = (int*)alloc((size_t)(NA + 1) * 4);
  int* slBA = (int*)alloc((size_t)E * 4);
  int* cntA = (int*)alloc((size_t)NA * 4);
  int* curA = (int*)alloc((size_t)NA * 4);
  int* cntB = (int*)alloc((size_t)NB * 4);
  int* curB = (int*)alloc((size_t)NB * 4);
  int* bsumA = (int*)alloc(256 * 4);
  int* bsumB = (int*)alloc(256 * 4);
  if (used > ws_size) return;  // diagnostic: absmax would equal max|ref| (~6.84)

  auto V = [&](int i) { return vec + 128 * i; };
  // vec slots: 0 pbA, 1 pbB, 2 as0ab, 3 ad0ab, 4 b0ab, 5 as0ba, 6 ad0ba,
  // 7 b0ba, 8 as1ab, 9 ad1ab, 10 b1ab, 11 as1ba, 12 ad1ba, 13 b1ba,
  // 14 g0A, 15 bn0A, 16 g0B, 17 bn0B, 18 g1A, 19 bn1A, 20 g1B, 21 bn1B

  ConvJobs jobs{};
  int nj = 0;
  auto addT = [&](const void* s, void* d, int K) {
    int ksh = (K == 128) ? 7 : 6;
    jobs.j[nj++] = ConvJob{s, d, 128 * K, 1, ksh};
  };
  auto addV = [&](const void* s, void* d) { jobs.j[nj++] = ConvJob{s, d, 128, 0, 7}; };
  addT(d_in[2], WcA, 128);
  addT(d_in[4], WcB, 64);
  addT(d_in[6], Wc0ab, 128);
  addT(d_in[10], Wc0ba, 128);
  addT(d_in[14], Wc1ab, 128);
  addT(d_in[18], Wc1ba, 128);
  const int vsrc[22] = {3, 5, 7, 8, 9, 11, 12, 13, 15, 16, 17, 19, 20, 21, 22, 23, 24, 25, 26, 27, 28, 29};
  for (int i = 0; i < 22; i++) addV(d_in[vsrc[i]], V(i));

  WtJobs4 wj{};
  wj.j[0] = WtJob{d_in[6],  d_in[8],  Wt0ab, 4};
  wj.j[1] = WtJob{d_in[10], d_in[12], Wt0ba, 4};
  wj.j[2] = WtJob{d_in[14], d_in[16], Wt1ab, 1};
  wj.j[3] = WtJob{d_in[18], d_in[20], Wt1ba, 1};

  const int nz = (NA + NB + 255) / 256;
  // D1: prep (flag, canonicalize, wtilde, cnt zero)
  prep_k<<<nj + 4 + nz, 256, 0, stream>>>((const unsigned*)d_in[0], flag, jobs, nj, wj,
                                          cntA, NA, cntB, NB);

  const int geh = (E + 255) / 256;
  const int gA = (NA + 63) / 64, gB = (NB + 63) / 64;
  const int aA = (NA + 3) / 4, aB = (NB + 3) / 4;
  const int nbB = (NB + 1023) / 1024, nbA = (NA + 1023) / 1024;

  // D2: hist (both dirs) ∥ input-projection GEMMs
  {
    GemmJob ja{d_in[0], WcA, V(0), nullptr, hA, nullptr, flag, nullptr, nullptr, NA, 128, 1, 0};
    GemmJob jb{d_in[1], WcB, V(1), nullptr, hB, nullptr, flag, nullptr, nullptr, NB, 64, 1, 0};
    histgemm_k<<<2 * geh + gA + gB, 256, 0, stream>>>(ja, jb, gA, dstAB, dstBA, E, geh,
                                                      cntB, cntA);
  }
  // D3: blocksum (parallel, both dirs) ∥ layer-0 GEMMs
  {
    GemmJob ja{hA, Wc0ab, nullptr, V(2), hsAB, asAB, nullptr, Wt0ba, adBA, NA, 128, 4, 4};
    GemmJob jb{hB, Wc0ba, nullptr, V(5), hsBA, asBA, nullptr, Wt0ab, adAB, NB, 128, 4, 4};
    bsumgemm_k<<<nbB + nbA + gA + gB, 256, 0, stream>>>(ja, jb, gA,
                                                        cntB, NB, bsumB, nbB,
                                                        cntA, NA, bsumA, nbA);
  }
  // D4: scan partials (2 tiny blocks)
  scanpart2_k<<<2, 256, 0, stream>>>(bsumB, nbB, bsumA, nbA);
  // D5: write row pointers
  writerp2_k<<<nbB + nbA, 256, 0, stream>>>(cntB, NB, bsumB, rpAB, curB, nbB,
                                            cntA, NA, bsumA, rpBA, curA);
  // D6: XCD-partitioned scatter (both dirs)
  {
    const int nsl = (2 * E + 2047) / 2048;
    scatter8_k<<<8 * nsl, 256, 0, stream>>>(srcAB, dstAB, srcBA, dstBA, E,
                                            curB, slAB, curA, slBA, NB, NA);
  }
  // D7: layer-0 aggregate (H=4, both dirs)
  {
    AggJob ja{rpAB, slAB, asAB, adAB, hsAB, V(4), V(16), V(17), hB, hB, nullptr, nullptr, 0, NB};
    AggJob jb{rpBA, slBA, asBA, adBA, hsBA, V(7), V(14), V(15), hA, hA, nullptr, nullptr, 0, NA};
    agg_k<4, false><<<aB + aA, 256, 0, stream>>>(ja, jb, aB);
  }
  // D8: layer-1 GEMMs
  {
    GemmJob ja{hA, Wc1ab, nullptr, V(8),  hsAB, asAB, nullptr, Wt1ba, adBA, NA, 128, 1, 1};
    GemmJob jb{hB, Wc1ba, nullptr, V(11), hsBA, asBA, nullptr, Wt1ab, adAB, NB, 128, 1, 1};
    gemm2_k<<<gA + gB, 256, 0, stream>>>(ja, jb, gA);
  }
  // D9: layer-1 aggregate (H=1, both dirs, final output)
  {
    AggJob ja{rpAB, slAB, asAB, adAB, hsAB, V(10), V(20), V(21), hB, nullptr, d_out, flag, NA, NB};
    AggJob jb{rpBA, slBA, asBA, adBA, hsBA, V(13), V(18), V(19), hA, nullptr, d_out, flag, 0, NA};
    agg_k<1, true><<<aB + aA, 256, 0, stream>>>(ja, jb, aB);
  }
}

// Round 6
// 465.216 us; speedup vs baseline: 1.2718x; 1.0047x over previous
//
#include <hip/hip_runtime.h>
#include <hip/hip_bf16.h>

using bf16 = __hip_bfloat16;
using frag8 = __attribute__((ext_vector_type(8))) short;  // 8 bf16 (4 VGPRs)
using f32x4 = __attribute__((ext_vector_type(4))) float;  // MFMA C/D

__device__ __forceinline__ short f2bf_bits(float f) {
  bf16 h = __float2bfloat16(f);
  short s; __builtin_memcpy(&s, &h, 2); return s;
}
__device__ __forceinline__ float bfbits2f(unsigned short u) {
  unsigned uu = (unsigned)u << 16; float f; __builtin_memcpy(&f, &uu, 4); return f;
}
__device__ __forceinline__ float wred_sum(float v) {
#pragma unroll
  for (int o = 32; o; o >>= 1) v += __shfl_xor(v, o);
  return v;
}

// ================= prep: flag-detect + param canonicalize + wtilde fold +
// cnt zeroing (counters are 8x binned now), all in ONE dispatch.
struct ConvJob { const void* src; void* dst; int n; int mode; int ksh; };
struct ConvJobs { ConvJob j[28]; };
struct WtJob { const void* wraw; const void* adraw; bf16* out; int H; };
struct WtJobs4 { WtJob j[4]; };

__global__ __launch_bounds__(256) void prep_k(
    const unsigned* __restrict__ xdet, int* __restrict__ flag,
    ConvJobs cjobs, int ncv, WtJobs4 wjobs,
    int* __restrict__ cntA, int nA8, int* __restrict__ cntB, int nB8)
{
  const int b = blockIdx.x, tid = threadIdx.x;
  if (b >= ncv + 4) {                         // cnt zero region (no flag needed)
    int i = (b - (ncv + 4)) * 256 + tid;
    if (i < nA8) cntA[i] = 0;
    else if (i < nA8 + nB8) cntB[i - nA8] = 0;
    return;
  }
  __shared__ int sh[256];
  int c = 0;
  for (int i = tid; i < 4096; i += 256) {
    unsigned bb = (xdet[i] >> 8) & 0x7F;
    c += (bb >= 0x3B && bb <= 0x41) ? 1 : 0;
  }
  sh[tid] = c; __syncthreads();
  for (int off = 128; off; off >>= 1) { if (tid < off) sh[tid] += sh[tid + off]; __syncthreads(); }
  const int f = (sh[0] < 2048) ? 1 : 0;
  if (b == 0 && tid == 0) flag[0] = f;

  if (b < ncv) {                              // canonicalize job
    ConvJob J = cjobs.j[b];
    const int Kt = 1 << J.ksh;
    for (int i = tid; i < J.n; i += 256) {
      int si = i;
      if (J.mode == 1) { int n = i >> J.ksh, k = i & (Kt - 1); si = k * 128 + n; }
      float v = f ? ((const float*)J.src)[si] : bfbits2f(((const unsigned short*)J.src)[si]);
      if (J.mode == 1) ((bf16*)J.dst)[i] = __float2bfloat16(v);
      else             ((float*)J.dst)[i] = v;
    }
  } else {                                    // wtilde fold from RAW W and ad
    WtJob J = wjobs.j[b - ncv];               // Wt2[h][k] = sum_d W[k][h*D+d]*ad[h*D+d]
    const int H = J.H, D = 128 / H;
    for (int idx = tid; idx < 16 * 128; idx += 256) {
      int h = idx >> 7, k = idx & 127;
      float s = 0.f;
      if (h < H) {
        for (int d = 0; d < D; d++) {
          int n = h * D + d;
          float wv = f ? ((const float*)J.wraw)[k * 128 + n]
                       : bfbits2f(((const unsigned short*)J.wraw)[k * 128 + n]);
          float av = f ? ((const float*)J.adraw)[n]
                       : bfbits2f(((const unsigned short*)J.adraw)[n]);
          s += wv * av;
        }
      }
      J.out[idx] = __float2bfloat16(s);
    }
  }
}

// ================= GEMM body (shared by merged kernels) =====================
struct GemmJob {
  const void* Av; const bf16* WT; const float* bias; const float* avec;
  bf16* outFull; float* outScore; const int* flagp;
  const bf16* WT2; float* outScore2;
  int M, K, H, H2;
};
__device__ __forceinline__ void gemm_body(const GemmJob& J, int blk) {
  __shared__ __align__(16) bf16 Wt[128 * 136];
  __shared__ __align__(16) bf16 Wt2s[16 * 136];
  const int tid = threadIdx.x;
  const int K = J.K;
  const int isf32 = J.flagp ? J.flagp[0] : 0;
  const int stride = K + 8;
  const int ksh2 = (K == 128) ? 4 : 3;
  const int kunits = K >> 3;
  for (int u = tid; u < 128 * kunits; u += 256) {
    int n = u >> ksh2, kb = u & (kunits - 1);
    frag8 v = *(const frag8*)(J.WT + n * K + kb * 8);
    *(frag8*)(Wt + n * stride + kb * 8) = v;
  }
  if (J.WT2) {
    int n = tid >> 4, kb = tid & 15;
    *(frag8*)(Wt2s + n * 136 + kb * 8) = *(const frag8*)(J.WT2 + n * 128 + kb * 8);
  }
  __syncthreads();

  const int lane = tid & 63, wave = tid >> 6;
  const int quad = lane >> 4, c = lane & 15;
  const int mbase = blk * 64 + wave * 16;
  const int arow = mbase + c;
  const bool rowOK = arow < J.M;

  f32x4 acc[8];
#pragma unroll
  for (int t = 0; t < 8; t++) acc[t] = (f32x4){0.f, 0.f, 0.f, 0.f};
  f32x4 acc2 = (f32x4){0.f, 0.f, 0.f, 0.f};

  for (int ks = 0; ks < K; ks += 32) {
    frag8 af;
    const int k0 = ks + quad * 8;
    if (rowOK) {
      if (isf32) {
        const float4* ap = (const float4*)((const float*)J.Av + (size_t)arow * K + k0);
        float4 v0 = ap[0], v1 = ap[1];
        af[0] = f2bf_bits(v0.x); af[1] = f2bf_bits(v0.y);
        af[2] = f2bf_bits(v0.z); af[3] = f2bf_bits(v0.w);
        af[4] = f2bf_bits(v1.x); af[5] = f2bf_bits(v1.y);
        af[6] = f2bf_bits(v1.z); af[7] = f2bf_bits(v1.w);
      } else {
        af = *(const frag8*)((const bf16*)J.Av + (size_t)arow * K + k0);
      }
    } else {
#pragma unroll
      for (int j = 0; j < 8; j++) af[j] = 0;
    }
#pragma unroll
    for (int t = 0; t < 8; t++) {
      frag8 bfv = *(const frag8*)(Wt + (t * 16 + c) * stride + k0);
      acc[t] = __builtin_amdgcn_mfma_f32_16x16x32_bf16(af, bfv, acc[t], 0, 0, 0);
    }
    if (J.WT2) {
      frag8 b2 = *(const frag8*)(Wt2s + c * 136 + k0);
      acc2 = __builtin_amdgcn_mfma_f32_16x16x32_bf16(af, b2, acc2, 0, 0, 0);
    }
  }

  if (J.outFull) {
#pragma unroll
    for (int t = 0; t < 8; t++) {
#pragma unroll
      for (int r = 0; r < 4; r++) {
        int orow = mbase + quad * 4 + r;
        if (orow < J.M) {
          float v = acc[t][r];
          if (J.bias) v += J.bias[t * 16 + c];
          J.outFull[(size_t)orow * 128 + t * 16 + c] = __float2bfloat16(v);
        }
      }
    }
  }
  if (J.outScore) {
    const int H = J.H;
    const int TPH = 8 / H;
    for (int hh = 0; hh < H; hh++) {
#pragma unroll
      for (int r = 0; r < 4; r++) {
        float p = 0.f;
        for (int tt = 0; tt < TPH; tt++) {
          int t = hh * TPH + tt;
          p += acc[t][r] * J.avec[t * 16 + c];
        }
#pragma unroll
        for (int off = 1; off < 16; off <<= 1) p += __shfl_xor(p, off);
        int orow = mbase + quad * 4 + r;
        if (c == 0 && orow < J.M) J.outScore[(size_t)orow * H + hh] = p;
      }
    }
  }
  if (J.outScore2) {
#pragma unroll
    for (int r = 0; r < 4; r++) {
      int orow = mbase + quad * 4 + r;
      if (c < J.H2 && orow < J.M) J.outScore2[(size_t)orow * J.H2 + c] = acc2[r];
    }
  }
}

// ================= hist ∥ proj-GEMM (one dispatch; binned key) ==============
__global__ __launch_bounds__(256) void histgemm_k(
    GemmJob ja, GemmJob jb, int gsplit,
    const int* __restrict__ sAB, const int* __restrict__ dAB,
    const int* __restrict__ sBA, const int* __restrict__ dBA, int E, int geh,
    int* __restrict__ cntB, int* __restrict__ cntA, int shA, int shB)
{
  const int b = blockIdx.x;
  if (b < 2 * geh) {
    if (b < geh) {
      int i = b * 256 + threadIdx.x;
      if (i < E) atomicAdd(&cntB[dAB[i] * 8 + (sAB[i] >> shA)], 1);
    } else {
      int i = (b - geh) * 256 + threadIdx.x;
      if (i < E) atomicAdd(&cntA[dBA[i] * 8 + (sBA[i] >> shB)], 1);
    }
    return;
  }
  const int gb = b - 2 * geh;
  if (gb < gsplit) gemm_body(ja, gb);
  else             gemm_body(jb, gb - gsplit);
}

// ================= scan: blocksum (raw sums) then writerp (self-offset) =====
__device__ __forceinline__ void blocksum_body(const int* cnt, int N, int* bsum, int blk) {
  __shared__ int sh[256];
  const int tid = threadIdx.x;
  const int beg = blk * 1024;
  const int end = (beg + 1024 < N) ? beg + 1024 : N;
  int loc = 0;
  for (int i = beg + tid; i < end; i += 256) loc += cnt[i];
  sh[tid] = loc; __syncthreads();
  for (int off = 128; off; off >>= 1) { if (tid < off) sh[tid] += sh[tid + off]; __syncthreads(); }
  if (tid == 0) bsum[blk] = sh[0];
}
__global__ __launch_bounds__(256) void blocksum2_k(
    const int* __restrict__ cntB, int NB8, int* __restrict__ bsumB, int nbB,
    const int* __restrict__ cntA, int NA8, int* __restrict__ bsumA)
{
  int b = blockIdx.x;
  if (b < nbB) blocksum_body(cntB, NB8, bsumB, b);
  else         blocksum_body(cntA, NA8, bsumA, b - nbB);
}
// writerp with integrated offset: offset = sum(bsum[0..blk)) — a reduction,
// computed per-block in parallel (no serial scan dispatch needed).
__device__ __forceinline__ void writerp_body(const int* cnt, int N, const int* bsum,
                                             int* rp, int* cur, int blk) {
  __shared__ int sh[256];
  const int tid = threadIdx.x;
  int offacc = 0;
  for (int i = tid; i < blk; i += 256) offacc += bsum[i];
  sh[tid] = offacc; __syncthreads();
  for (int off = 128; off; off >>= 1) { if (tid < off) sh[tid] += sh[tid + off]; __syncthreads(); }
  const int base = sh[0];
  __syncthreads();

  const int idx0 = blk * 1024 + tid * 4;
  int c[4]; int loc = 0;
#pragma unroll
  for (int j = 0; j < 4; j++) {
    int i = idx0 + j;
    c[j] = (i < N) ? cnt[i] : 0;
    loc += c[j];
  }
  sh[tid] = loc; __syncthreads();
  for (int off = 1; off < 256; off <<= 1) {
    int x = sh[tid];
    int o = (tid >= off) ? sh[tid - off] : 0;
    __syncthreads();
    sh[tid] = x + o;
    __syncthreads();
  }
  int run = base + ((tid == 0) ? 0 : sh[tid - 1]);
#pragma unroll
  for (int j = 0; j < 4; j++) {
    int i = idx0 + j;
    if (i < N) { rp[i] = run; cur[i] = run; }
    run += c[j];
  }
  if (idx0 <= N - 1 && N - 1 < idx0 + 4) rp[N] = run;  // total
}
__global__ __launch_bounds__(256) void writerp2_k(
    const int* __restrict__ cntB, int NB8, const int* __restrict__ bsumB,
    int* __restrict__ rpAB, int* __restrict__ curB, int nbB,
    const int* __restrict__ cntA, int NA8, const int* __restrict__ bsumA,
    int* __restrict__ rpBA, int* __restrict__ curA)
{
  int b = blockIdx.x;
  if (b < nbB) writerp_body(cntB, NB8, bsumB, rpAB, curB, b);
  else         writerp_body(cntA, NA8, bsumA, rpBA, curA, b - nbB);
}

// plain dual-GEMM dispatch (layer 1)
__global__ __launch_bounds__(256) void gemm2_k(GemmJob ja, GemmJob jb, int split) {
  if (blockIdx.x < split) gemm_body(ja, blockIdx.x);
  else                    gemm_body(jb, blockIdx.x - split);
}

// ================= scatter (XCD-partitioned, binned key) ∥ layer-0 GEMM =====
// gemm blocks FIRST in the grid (fewer, start immediately), scatter fills rest.
__global__ __launch_bounds__(256) void scattgemm_k(
    GemmJob ja, GemmJob jb, int gsplit, int gtot,
    const int* __restrict__ sAB, const int* __restrict__ dAB,
    const int* __restrict__ sBA, const int* __restrict__ dBA, int E,
    int* __restrict__ curB, int* __restrict__ slAB,
    int* __restrict__ curA, int* __restrict__ slBA, int NB, int NA,
    int shA, int shB)
{
  int b = blockIdx.x;
  if (b < gtot) {
    if (b < gsplit) gemm_body(ja, b);
    else            gemm_body(jb, b - gsplit);
    return;
  }
  b -= gtot;
  const int g = b & 7;
  const int sidx = b >> 3;
  const int loB = (int)((long long)NB * g >> 3), hiB = (int)((long long)NB * (g + 1) >> 3);
  const int loA = (int)((long long)NA * g >> 3), hiA = (int)((long long)NA * (g + 1) >> 3);
  const int b0 = sidx * 2048;
#pragma unroll
  for (int j = 0; j < 8; j++) {
    int i = b0 + j * 256 + threadIdx.x;
    if (i < 2 * E) {
      bool ab = i < E;
      int k = ab ? i : i - E;
      int d = ab ? dAB[k] : dBA[k];
      int lo = ab ? loB : loA, hi = ab ? hiB : hiA;
      if (d >= lo && d < hi) {
        int sv = ab ? sAB[k] : sBA[k];
        int key = d * 8 + (sv >> (ab ? shA : shB));
        int pos = atomicAdd((ab ? curB : curA) + key, 1);
        (ab ? slAB : slBA)[pos] = sv;
      }
    }
  }
}

// ================= GAT aggregate (dual-edge; src-binned edge order) =========
// Node n's edges live in [rp[8n], rp[8n+8]) sorted by src-octant — concurrent
// blocks gather from the same ~1.6MB hs slice => L2-resident gathers.
struct AggJob {
  const int* rp; const int* srcl; const float* as_; const float* ad_;
  const bf16* hs; const float* bias; const float* gamma; const float* beta;
  const bf16* resid; bf16* outBf; void* outFinal; const int* flagp;
  int nodeBase, N;
};

template<bool FINAL>
__device__ __forceinline__ void agg_epi4(const AggJob& J, int n, int hl, int half,
                                         float inv, float a0, float a1, float a2, float a3) {
  float4 bi = *(const float4*)(J.bias + 4 * hl);
  float y0 = a0 * inv + bi.x;
  float y1 = a1 * inv + bi.y;
  float y2 = a2 * inv + bi.z;
  float y3 = a3 * inv + bi.w;
  float tsum = wred_sum(y0 + y1 + y2 + y3);          // halves duplicated: 2x
  float tsq  = wred_sum(y0 * y0 + y1 * y1 + y2 * y2 + y3 * y3);
  float mu = tsum * 0.00390625f;                     // 1/256
  float var = tsq * 0.00390625f - mu * mu;
  float rs = rsqrtf(var + 1e-5f);
  float4 ga = *(const float4*)(J.gamma + 4 * hl);
  float4 be = *(const float4*)(J.beta + 4 * hl);
  float z0 = (y0 - mu) * rs * ga.x + be.x;
  float z1 = (y1 - mu) * rs * ga.y + be.y;
  float z2 = (y2 - mu) * rs * ga.z + be.z;
  float z3 = (y3 - mu) * rs * ga.w + be.w;
  uint2 ru = *(const uint2*)(J.resid + (size_t)n * 128 + hl * 4);
  z0 = fmaxf(z0, 0.f) + bfbits2f((unsigned short)(ru.x & 0xFFFF));
  z1 = fmaxf(z1, 0.f) + bfbits2f((unsigned short)(ru.x >> 16));
  z2 = fmaxf(z2, 0.f) + bfbits2f((unsigned short)(ru.y & 0xFFFF));
  z3 = fmaxf(z3, 0.f) + bfbits2f((unsigned short)(ru.y >> 16));
  if (half == 0) {
    if constexpr (FINAL) {
      size_t oi = (size_t)(J.nodeBase + n) * 128 + hl * 4;
      if (J.flagp[0]) {
        *(float4*)((float*)J.outFinal + oi) = make_float4(z0, z1, z2, z3);
      } else {
        uint2 pk;
        pk.x = (unsigned)(unsigned short)f2bf_bits(z0) | ((unsigned)(unsigned short)f2bf_bits(z1) << 16);
        pk.y = (unsigned)(unsigned short)f2bf_bits(z2) | ((unsigned)(unsigned short)f2bf_bits(z3) << 16);
        *(uint2*)((bf16*)J.outFinal + oi) = pk;
      }
    } else {
      uint2 pk;
      pk.x = (unsigned)(unsigned short)f2bf_bits(z0) | ((unsigned)(unsigned short)f2bf_bits(z1) << 16);
      pk.y = (unsigned)(unsigned short)f2bf_bits(z2) | ((unsigned)(unsigned short)f2bf_bits(z3) << 16);
      *(uint2*)(J.outBf + (size_t)n * 128 + hl * 4) = pk;
    }
  }
}

template<int H, bool FINAL>
__global__ __launch_bounds__(256) void agg_k(AggJob JA, AggJob JB, int split) {
  const bool first = blockIdx.x < split;
  const AggJob J = first ? JA : JB;
  const int blk = first ? blockIdx.x : blockIdx.x - split;

  __shared__ int   s_src[4][64];
  __shared__ float s_p[4][64 * H];
  const int tid = threadIdx.x;
  const int wave = tid >> 6, lane = tid & 63;
  const int n = blk * 4 + wave;
  if (n >= J.N) return;                        // no block barriers below

  const int beg = J.rp[(size_t)n * 8], end = J.rp[(size_t)n * 8 + 8];
  const int half = lane >> 5;                  // which edge of the pair
  const int hl = lane & 31;                    // dim group: elems 4*hl..4*hl+3
  const int myh = (H == 4) ? (hl >> 3) : 0;

  float4 adv;
  if (H == 4) adv = *(const float4*)(J.ad_ + (size_t)n * 4);
  else        adv.x = J.ad_[n];

  float sl_[H];
#pragma unroll
  for (int h = 0; h < H; h++) sl_[h] = 0.f;
  float a0 = 0.f, a1 = 0.f, a2 = 0.f, a3 = 0.f;
  const int* srcp = J.srcl;
  const float* asp = J.as_;
  const bf16* hsp = J.hs;

  for (int base = beg; base < end; base += 64) {
    const int cn = (end - base < 64) ? end - base : 64;
    if (lane < cn) {
      int s = srcp[base + lane];
      s_src[wave][lane] = s;
      if (H == 4) {
        float4 a = *(const float4*)(asp + (size_t)s * 4);
        float4 o; float v;
        v = a.x + adv.x; v = v > 0.f ? v : 0.2f * v; o.x = __expf(v);
        v = a.y + adv.y; v = v > 0.f ? v : 0.2f * v; o.y = __expf(v);
        v = a.z + adv.z; v = v > 0.f ? v : 0.2f * v; o.z = __expf(v);
        v = a.w + adv.w; v = v > 0.f ? v : 0.2f * v; o.w = __expf(v);
        *(float4*)&s_p[wave][lane * 4] = o;
        sl_[0] += o.x; sl_[1] += o.y; sl_[2] += o.z; sl_[3] += o.w;
      } else {
        float v = asp[s] + adv.x;
        v = v > 0.f ? v : 0.2f * v;
        float pv = __expf(v);
        s_p[wave][lane] = pv;
        sl_[0] += pv;
      }
    }
    __builtin_amdgcn_wave_barrier();
    const int cne = cn & ~1;
#pragma unroll 4
    for (int e = 0; e < cne; e += 2) {
      const int eidx = e + half;
      const int s = s_src[wave][eidx];
      const float p = s_p[wave][eidx * H + myh];
      const uint2 u = *(const uint2*)(hsp + (size_t)s * 128 + hl * 4);
      a0 += p * bfbits2f((unsigned short)(u.x & 0xFFFF));
      a1 += p * bfbits2f((unsigned short)(u.x >> 16));
      a2 += p * bfbits2f((unsigned short)(u.y & 0xFFFF));
      a3 += p * bfbits2f((unsigned short)(u.y >> 16));
    }
    if (cn & 1) {                              // odd tail: half 1 contributes 0
      const int eidx = cn - 1;
      const int s = s_src[wave][eidx];
      const float p = half ? 0.f : s_p[wave][eidx * H + myh];
      const uint2 u = *(const uint2*)(hsp + (size_t)s * 128 + hl * 4);
      a0 += p * bfbits2f((unsigned short)(u.x & 0xFFFF));
      a1 += p * bfbits2f((unsigned short)(u.x >> 16));
      a2 += p * bfbits2f((unsigned short)(u.y & 0xFFFF));
      a3 += p * bfbits2f((unsigned short)(u.y >> 16));
    }
    __builtin_amdgcn_wave_barrier();
  }

  // combine the two half-wave edge partitions
  a0 += __shfl_xor(a0, 32);
  a1 += __shfl_xor(a1, 32);
  a2 += __shfl_xor(a2, 32);
  a3 += __shfl_xor(a3, 32);

  float s = 0.f;
#pragma unroll
  for (int h = 0; h < H; h++) {
    float t = wred_sum(sl_[h]);
    if (h == myh) s = t;
  }
  const float inv = 1.f / (s + 1e-16f);
  agg_epi4<FINAL>(J, n, hl, half, inv, a0, a1, a2, a3);
}

extern "C" void kernel_launch(void* const* d_in, const int* in_sizes, int n_in,
                              void* d_out, int out_size, void* d_ws, size_t ws_size,
                              hipStream_t stream)
{
  const int NA = in_sizes[0] / 128;
  const int NB = in_sizes[1] / 64;
  const int E  = in_sizes[30] / 2;
  const int* eiAB = (const int*)d_in[30];
  const int* eiBA = (const int*)d_in[31];
  const int* srcAB = eiAB;  const int* dstAB = eiAB + E;
  const int* srcBA = eiBA;  const int* dstBA = eiBA + E;

  // src-octant shifts (bins = src >> sh, in [0,8))
  int shA = 0; while (((NA - 1) >> shA) > 7) shA++;
  int shB = 0; while (((NB - 1) >> shB) > 7) shB++;

  char* w = (char*)d_ws;
  size_t used = 0;
  auto alloc = [&](size_t bytes) {
    char* p = w + used;
    used += (bytes + 255) & ~size_t(255);
    return (void*)p;
  };
  int*  flag  = (int*)alloc(256);
  bf16* WcA   = (bf16*)alloc(16384 * 2);
  bf16* WcB   = (bf16*)alloc(8192 * 2);
  bf16* Wc0ab = (bf16*)alloc(16384 * 2);
  bf16* Wc0ba = (bf16*)alloc(16384 * 2);
  bf16* Wc1ab = (bf16*)alloc(16384 * 2);
  bf16* Wc1ba = (bf16*)alloc(16384 * 2);
  bf16* Wt0ab = (bf16*)alloc(16 * 128 * 2);    // folded W*ad tiles
  bf16* Wt0ba = (bf16*)alloc(16 * 128 * 2);
  bf16* Wt1ab = (bf16*)alloc(16 * 128 * 2);
  bf16* Wt1ba = (bf16*)alloc(16 * 128 * 2);
  float* vec  = (float*)alloc(22 * 128 * 4);
  bf16* hA    = (bf16*)alloc((size_t)NA * 128 * 2);
  bf16* hB    = (bf16*)alloc((size_t)NB * 128 * 2);
  bf16* hsAB  = (bf16*)alloc((size_t)NA * 128 * 2);
  bf16* hsBA  = (bf16*)alloc((size_t)NB * 128 * 2);
  float* asAB = (float*)alloc((size_t)NA * 4 * 4);
  float* adAB = (float*)alloc((size_t)NB * 4 * 4);
  float* asBA = (float*)alloc((size_t)NB * 4 * 4);
  float* adBA = (float*)alloc((size_t)NA * 4 * 4);
  int* rpAB = (int*)alloc(((size_t)NB * 8 + 1) * 4);
  int* slAB = (int*)alloc((size_t)E * 4);
  int* rpBA = (int*)alloc(((size_t)NA * 8 + 1) * 4);
  int* slBA = (int*)alloc((size_t)E * 4);
  int* cntA = (int*)alloc((size_t)NA * 8 * 4);
  int* curA = (int*)alloc((size_t)NA * 8 * 4);
  int* cntB = (int*)alloc((size_t)NB * 8 * 4);
  int* curB = (int*)alloc((size_t)NB * 8 * 4);
  int* bsumA = (int*)alloc(1024 * 4);
  int* bsumB = (int*)alloc(1024 * 4);
  if (used > ws_size) return;  // diagnostic: absmax would equal max|ref| (~6.84)

  auto V = [&](int i) { return vec + 128 * i; };
  // vec slots: 0 pbA, 1 pbB, 2 as0ab, 3 ad0ab, 4 b0ab, 5 as0ba, 6 ad0ba,
  // 7 b0ba, 8 as1ab, 9 ad1ab, 10 b1ab, 11 as1ba, 12 ad1ba, 13 b1ba,
  // 14 g0A, 15 bn0A, 16 g0B, 17 bn0B, 18 g1A, 19 bn1A, 20 g1B, 21 bn1B

  ConvJobs jobs{};
  int nj = 0;
  auto addT = [&](const void* s, void* d, int K) {
    int ksh = (K == 128) ? 7 : 6;
    jobs.j[nj++] = ConvJob{s, d, 128 * K, 1, ksh};
  };
  auto addV = [&](const void* s, void* d) { jobs.j[nj++] = ConvJob{s, d, 128, 0, 7}; };
  addT(d_in[2], WcA, 128);
  addT(d_in[4], WcB, 64);
  addT(d_in[6], Wc0ab, 128);
  addT(d_in[10], Wc0ba, 128);
  addT(d_in[14], Wc1ab, 128);
  addT(d_in[18], Wc1ba, 128);
  const int vsrc[22] = {3, 5, 7, 8, 9, 11, 12, 13, 15, 16, 17, 19, 20, 21, 22, 23, 24, 25, 26, 27, 28, 29};
  for (int i = 0; i < 22; i++) addV(d_in[vsrc[i]], V(i));

  WtJobs4 wj{};
  wj.j[0] = WtJob{d_in[6],  d_in[8],  Wt0ab, 4};
  wj.j[1] = WtJob{d_in[10], d_in[12], Wt0ba, 4};
  wj.j[2] = WtJob{d_in[14], d_in[16], Wt1ab, 1};
  wj.j[3] = WtJob{d_in[18], d_in[20], Wt1ba, 1};

  const int NA8 = NA * 8, NB8 = NB * 8;
  const int nz = (NA8 + NB8 + 255) / 256;
  // D1: prep (flag, canonicalize, wtilde, cnt zero)
  prep_k<<<nj + 4 + nz, 256, 0, stream>>>((const unsigned*)d_in[0], flag, jobs, nj, wj,
                                          cntA, NA8, cntB, NB8);

  const int geh = (E + 255) / 256;
  const int gA = (NA + 63) / 64, gB = (NB + 63) / 64;
  const int aA = (NA + 3) / 4, aB = (NB + 3) / 4;
  const int nbB = (NB8 + 1023) / 1024, nbA = (NA8 + 1023) / 1024;

  // D2: hist (both dirs, binned key) ∥ input-projection GEMMs
  {
    GemmJob ja{d_in[0], WcA, V(0), nullptr, hA, nullptr, flag, nullptr, nullptr, NA, 128, 1, 0};
    GemmJob jb{d_in[1], WcB, V(1), nullptr, hB, nullptr, flag, nullptr, nullptr, NB, 64, 1, 0};
    histgemm_k<<<2 * geh + gA + gB, 256, 0, stream>>>(ja, jb, gA,
                                                      srcAB, dstAB, srcBA, dstBA, E, geh,
                                                      cntB, cntA, shA, shB);
  }
  // D3: blocksum (raw per-chunk sums)
  blocksum2_k<<<nbB + nbA, 256, 0, stream>>>(cntB, NB8, bsumB, nbB, cntA, NA8, bsumA);
  // D4: writerp (self-computed offsets; no scan dispatch)
  writerp2_k<<<nbB + nbA, 256, 0, stream>>>(cntB, NB8, bsumB, rpAB, curB, nbB,
                                            cntA, NA8, bsumA, rpBA, curA);
  // D5: layer-0 GEMMs ∥ XCD-partitioned scatter (gemm blocks first)
  {
    GemmJob ja{hA, Wc0ab, nullptr, V(2), hsAB, asAB, nullptr, Wt0ba, adBA, NA, 128, 4, 4};
    GemmJob jb{hB, Wc0ba, nullptr, V(5), hsBA, asBA, nullptr, Wt0ab, adAB, NB, 128, 4, 4};
    const int gtot = gA + gB;
    const int nsl = (2 * E + 2047) / 2048;
    scattgemm_k<<<gtot + 8 * nsl, 256, 0, stream>>>(ja, jb, gA, gtot,
                                                    srcAB, dstAB, srcBA, dstBA, E,
                                                    curB, slAB, curA, slBA, NB, NA,
                                                    shA, shB);
  }
  // D6: layer-0 aggregate (H=4, both dirs)
  {
    AggJob ja{rpAB, slAB, asAB, adAB, hsAB, V(4), V(16), V(17), hB, hB, nullptr, nullptr, 0, NB};
    AggJob jb{rpBA, slBA, asBA, adBA, hsBA, V(7), V(14), V(15), hA, hA, nullptr, nullptr, 0, NA};
    agg_k<4, false><<<aB + aA, 256, 0, stream>>>(ja, jb, aB);
  }
  // D7: layer-1 GEMMs
  {
    GemmJob ja{hA, Wc1ab, nullptr, V(8),  hsAB, asAB, nullptr, Wt1ba, adBA, NA, 128, 1, 1};
    GemmJob jb{hB, Wc1ba, nullptr, V(11), hsBA, asBA, nullptr, Wt1ab, adAB, NB, 128, 1, 1};
    gemm2_k<<<gA + gB, 256, 0, stream>>>(ja, jb, gA);
  }
  // D8: layer-1 aggregate (H=1, both dirs, final output)
  {
    AggJob ja{rpAB, slAB, asAB, adAB, hsAB, V(10), V(20), V(21), hB, nullptr, d_out, flag, NA, NB};
    AggJob jb{rpBA, slBA, asBA, adBA, hsBA, V(13), V(18), V(19), hA, nullptr, d_out, flag, 0, NA};
    agg_k<1, true><<<aB + aA, 256, 0, stream>>>(ja, jb, aB);
  }
}